// Round 9
// baseline (1241.257 us; speedup 1.0000x reference)
//
#include <hip/hip_runtime.h>
#include <math.h>

#define N_ATOMS 50000
#define N_EDGES 800000
#define F 64
#define Z 192
#define NCONV 3
#define T_TGT 4096
#define EPS 1e-5f
#define SLOTS 64
#define NB_SCAN 196          // ceil(50000/256)
#define NBLK_E 1250          // edge kernel blocks: 1250*4 waves*10 steps*16 = 800000
#define STEPS_E 10
#define NGRP_N 3125          // 50000/16 node groups
#define NBLK_N 782           // ceil(3125/4)

typedef __attribute__((ext_vector_type(4))) float f32x4;
typedef __attribute__((ext_vector_type(8))) short s16x8;
typedef __attribute__((ext_vector_type(8))) __bf16 bf16x8;

static __device__ __forceinline__ float bf2f(unsigned short u) {
    return __uint_as_float(((unsigned int)u) << 16);
}
static __device__ __forceinline__ unsigned short f2bf(float f) {
    unsigned int u = __float_as_uint(f);
    unsigned int r = u + 0x7FFFu + ((u >> 16) & 1u);
    return (unsigned short)(r >> 16);
}
static __device__ __forceinline__ bf16x8 pack8(float4 a, float4 b) {
    s16x8 r;
    r[0] = (short)f2bf(a.x); r[1] = (short)f2bf(a.y);
    r[2] = (short)f2bf(a.z); r[3] = (short)f2bf(a.w);
    r[4] = (short)f2bf(b.x); r[5] = (short)f2bf(b.y);
    r[6] = (short)f2bf(b.z); r[7] = (short)f2bf(b.w);
    return __builtin_bit_cast(bf16x8, r);
}
static __device__ __forceinline__ uint2 pack4(float a, float b, float c, float d) {
    uint2 r;
    r.x = (unsigned int)f2bf(a) | ((unsigned int)f2bf(b) << 16);
    r.y = (unsigned int)f2bf(c) | ((unsigned int)f2bf(d) << 16);
    return r;
}

// ---------------- preprocessing ----------------

__global__ void k_embed(const int* __restrict__ types, const float* __restrict__ emb,
                        float* __restrict__ x, unsigned short* __restrict__ xb) {
    int idx = blockIdx.x * 256 + threadIdx.x;
    if (idx < N_ATOMS * F) {
        int n = idx >> 6, f = idx & 63;
        float v = emb[types[n] * F + f];
        x[idx] = v;
        xb[idx] = f2bf(v);
    }
}

__global__ void k_degree(const int* __restrict__ idx_i, int* __restrict__ cnt) {
    int e = blockIdx.x * 256 + threadIdx.x;
    if (e < N_EDGES) atomicAdd(&cnt[idx_i[e]], 1);
}

__global__ void k_scanA(const int* __restrict__ cnt, int* __restrict__ bsum) {
    __shared__ int s[256];
    int base = blockIdx.x * 256, t = threadIdx.x;
    s[t] = (base + t < N_ATOMS) ? cnt[base + t] : 0;
    __syncthreads();
    for (int o = 128; o > 0; o >>= 1) {
        if (t < o) s[t] += s[t + o];
        __syncthreads();
    }
    if (t == 0) bsum[blockIdx.x] = s[0];
}

__global__ void k_scanB(int* __restrict__ bsum, int* __restrict__ rowptr) {
    __shared__ int s[256];
    int t = threadIdx.x;
    int v = (t < NB_SCAN) ? bsum[t] : 0;
    s[t] = v;
    __syncthreads();
    for (int o = 1; o < 256; o <<= 1) {
        int add = (t >= o) ? s[t - o] : 0;
        __syncthreads();
        s[t] += add;
        __syncthreads();
    }
    if (t < NB_SCAN) bsum[t] = s[t] - v;  // exclusive
    if (t == 0) rowptr[N_ATOMS] = N_EDGES;
}

__global__ void k_scanC(const int* __restrict__ cnt, const int* __restrict__ bsum,
                        int* __restrict__ rowptr) {
    __shared__ int s[256];
    int base = blockIdx.x * 256, t = threadIdx.x;
    int v = (base + t < N_ATOMS) ? cnt[base + t] : 0;
    s[t] = v;
    __syncthreads();
    for (int o = 1; o < 256; o <<= 1) {
        int add = (t >= o) ? s[t - o] : 0;
        __syncthreads();
        s[t] += add;
        __syncthreads();
    }
    if (base + t < N_ATOMS) rowptr[base + t] = bsum[blockIdx.x] + s[t] - v;
}

__global__ void k_scatter(const int* __restrict__ idx_i, const int* __restrict__ idx_j,
                          const int* __restrict__ rowptr, int* __restrict__ wofs,
                          int* __restrict__ i_s, int* __restrict__ j_s,
                          int* __restrict__ einv) {
    int e = blockIdx.x * 256 + threadIdx.x;
    if (e < N_EDGES) {
        int i = idx_i[e];
        int pos = rowptr[i] + atomicAdd(&wofs[i], 1);
        i_s[pos] = i;
        j_s[pos] = idx_j[e];
        einv[e] = pos;              // inverse perm: original edge -> CSR slot
    }
}

// edge_attr -> bf16 into CSR slot. 8 lanes per row: reads are wave-contiguous
// (2 KB/wave), each dest 128-B line is covered by ONE store instruction.
__global__ void k_prep2(const float* __restrict__ ea, const int* __restrict__ einv,
                        unsigned short* __restrict__ eab) {
    int idx = blockIdx.x * 256 + threadIdx.x;
    int row = idx >> 3;
    if (row >= N_EDGES) return;
    int seg = (idx & 7) * 8;
    const float* src = ea + (size_t)row * F + seg;
    float4 a = *(const float4*)src;
    float4 b = *(const float4*)(src + 4);
    int pos = einv[row];
    *(bf16x8*)(eab + (size_t)pos * F + seg) = pack8(a, b);
}

// ---------------- per-layer: node projections (MFMA) ----------------
// u[n] = x[n] @ Wc[:,0:64]^T   (fp32)
// v[n] = x[n] @ Wc[:,64:128]^T (bf16)
// pi[n] = x[n].Wf[0:64], pj[n] = x[n].Wf[64:128]
__global__ __launch_bounds__(256) void k_node_mm(
    const unsigned short* __restrict__ xb,
    const float* __restrict__ Wc, const float* __restrict__ Wf,
    float* __restrict__ u, unsigned short* __restrict__ v,
    float* __restrict__ pi, float* __restrict__ pj)
{
    __shared__ unsigned short WL[18 * 64 * 8];   // 9 KB: frag f = kt*9+m
    int t = threadIdx.x;
    int lane = t & 63, w = t >> 6;
    int c = lane & 15, g = lane >> 4;
    int goff = g * 8;

    #pragma unroll
    for (int rep = 0; rep < 5; ++rep) {
        int f = rep * 4 + w;
        if (f < 18) {
            int kt = f / 9, m = f % 9;           // wave-uniform
            bf16x8 val;
            if (m < 8) {
                int colbase = (m < 4) ? 0 : 64;
                const float* wp = Wc + (size_t)((m & 3) * 16 + c) * Z + colbase + kt * 32 + goff;
                val = pack8(*(const float4*)wp, *(const float4*)(wp + 4));
            } else {
                s16x8 zz = {0, 0, 0, 0, 0, 0, 0, 0};
                val = __builtin_bit_cast(bf16x8, zz);
                if (c == 0) {
                    const float* wp = Wf + kt * 32 + goff;
                    val = pack8(*(const float4*)wp, *(const float4*)(wp + 4));
                } else if (c == 1) {
                    const float* wp = Wf + 64 + kt * 32 + goff;
                    val = pack8(*(const float4*)wp, *(const float4*)(wp + 4));
                }
            }
            *(bf16x8*)(WL + ((size_t)f * 64 + lane) * 8) = val;
        }
    }
    __syncthreads();

    int grp = blockIdx.x * 4 + w;
    if (grp >= NGRP_N) return;
    int node = grp * 16 + c;
    const unsigned short* xr = xb + (size_t)node * F;
    bf16x8 X0 = *(const bf16x8*)(xr + goff);
    bf16x8 X1 = *(const bf16x8*)(xr + 32 + goff);

    #define LFR(f) (*(const bf16x8*)(WL + ((size_t)(f) * 64 + lane) * 8))
    f32x4 au[4], av[4], ap = (f32x4){0.f, 0.f, 0.f, 0.f};
    #pragma unroll
    for (int m = 0; m < 4; ++m) {
        au[m] = (f32x4){0.f, 0.f, 0.f, 0.f};
        av[m] = (f32x4){0.f, 0.f, 0.f, 0.f};
        au[m] = __builtin_amdgcn_mfma_f32_16x16x32_bf16(LFR(m), X0, au[m], 0, 0, 0);
        au[m] = __builtin_amdgcn_mfma_f32_16x16x32_bf16(LFR(9 + m), X1, au[m], 0, 0, 0);
        av[m] = __builtin_amdgcn_mfma_f32_16x16x32_bf16(LFR(4 + m), X0, av[m], 0, 0, 0);
        av[m] = __builtin_amdgcn_mfma_f32_16x16x32_bf16(LFR(13 + m), X1, av[m], 0, 0, 0);
    }
    ap = __builtin_amdgcn_mfma_f32_16x16x32_bf16(LFR(8), X0, ap, 0, 0, 0);
    ap = __builtin_amdgcn_mfma_f32_16x16x32_bf16(LFR(17), X1, ap, 0, 0, 0);
    #undef LFR

    float* urow = u + (size_t)node * F + g * 4;
    unsigned short* vrow = v + (size_t)node * F + g * 4;
    #pragma unroll
    for (int m = 0; m < 4; ++m) {
        *(f32x4*)(urow + m * 16) = au[m];
        *(uint2*)(vrow + m * 16) = pack4(av[m][0], av[m][1], av[m][2], av[m][3]);
    }
    if (g == 0) {
        pi[node] = ap[0];
        pj[node] = ap[1];
    }
}

// ---------------- per-layer: edge kernel (streaming K=64 MFMA + row adds) ----------------
// D[row=feat, col=edge]: lane (c,g) owns edge base+c, feats nt*16+g*4+q.
// nt==4 is the filt column: A-rows = (row0: Wf[128:192], rest 0).
// Plain loop: compiler fully unrolls the 10 steps and schedules loads ahead.
// launch_bounds(256,6): VGPR cap 85 (measured 84) -> 6 blocks/CU for latency hiding.
__global__ __launch_bounds__(256, 6) void k_edge2(
    const unsigned short* __restrict__ eab,
    const float* __restrict__ u, const unsigned short* __restrict__ v,
    const int* __restrict__ i_s, const int* __restrict__ j_s,
    const float* __restrict__ Wc, const float* __restrict__ Wf,
    const float* __restrict__ pi, const float* __restrict__ pj,
    unsigned short* __restrict__ y, float* __restrict__ filt,
    float* __restrict__ stats)
{
    __shared__ unsigned short WL[10 * 64 * 8];   // 10 frags: f = kt*5+nt
    int t = threadIdx.x;
    int lane = t & 63, w = t >> 6;
    int c = lane & 15, g = lane >> 4;
    int goff = g * 8;

    #pragma unroll
    for (int rep = 0; rep < 3; ++rep) {
        int f = rep * 4 + w;                     // 0..11, wave-uniform
        if (f < 10) {
            int kt = f / 5, nt = f % 5;
            bf16x8 val;
            if (nt < 4) {
                const float* wp = Wc + (size_t)(nt * 16 + c) * Z + 128 + kt * 32 + goff;
                val = pack8(*(const float4*)wp, *(const float4*)(wp + 4));
            } else {
                s16x8 zz = {0, 0, 0, 0, 0, 0, 0, 0};
                val = __builtin_bit_cast(bf16x8, zz);
                if (c == 0) {
                    const float* wp = Wf + 128 + kt * 32 + goff;
                    val = pack8(*(const float4*)wp, *(const float4*)(wp + 4));
                }
            }
            *(bf16x8*)(WL + ((size_t)f * 64 + lane) * 8) = val;
        }
    }
    __syncthreads();

    bf16x8 A[2][5];
    #pragma unroll
    for (int kt = 0; kt < 2; ++kt)
        #pragma unroll
        for (int nt = 0; nt < 5; ++nt)
            A[kt][nt] = *(const bf16x8*)(WL + ((size_t)(kt * 5 + nt) * 64 + lane) * 8);

    float ssum[4][4] = {{0.f}}, ssq[4][4] = {{0.f}};

    int e = blockIdx.x * (STEPS_E * 64) + w * 16 + c;
    int ie = i_s[e], je = j_s[e];
    bf16x8 E0 = *(const bf16x8*)(eab + (size_t)e * F + goff);
    bf16x8 E1 = *(const bf16x8*)(eab + (size_t)e * F + 32 + goff);

    for (int s = 0; s < STEPS_E; ++s) {
        // u/v row loads for current edge (addresses ready since last iter)
        const float* ur = u + (size_t)ie * F + g * 4;
        const unsigned short* vr = v + (size_t)je * F + g * 4;
        float4 uu[4];
        uint2 vv[4];
        #pragma unroll
        for (int nt = 0; nt < 4; ++nt) {
            uu[nt] = *(const float4*)(ur + nt * 16);
            vv[nt] = *(const uint2*)(vr + nt * 16);
        }
        float fi = 0.f, fj = 0.f;
        if (g == 0) { fi = pi[ie]; fj = pj[je]; }

        // prefetch next step
        int e2 = e, ie2 = ie, je2 = je;
        bf16x8 E0n = E0, E1n = E1;
        if (s + 1 < STEPS_E) {
            e2 = e + 64;
            ie2 = i_s[e2];
            je2 = j_s[e2];
            E0n = *(const bf16x8*)(eab + (size_t)e2 * F + goff);
            E1n = *(const bf16x8*)(eab + (size_t)e2 * F + 32 + goff);
        }

        f32x4 acc[5];
        #pragma unroll
        for (int nt = 0; nt < 5; ++nt) {
            acc[nt] = (f32x4){0.f, 0.f, 0.f, 0.f};
            acc[nt] = __builtin_amdgcn_mfma_f32_16x16x32_bf16(A[0][nt], E0, acc[nt], 0, 0, 0);
            acc[nt] = __builtin_amdgcn_mfma_f32_16x16x32_bf16(A[1][nt], E1, acc[nt], 0, 0, 0);
        }

        unsigned short* yr = y + (size_t)e * F + g * 4;
        #pragma unroll
        for (int nt = 0; nt < 4; ++nt) {
            float y0 = acc[nt][0] + uu[nt].x + bf2f((unsigned short)(vv[nt].x & 0xffff));
            float y1 = acc[nt][1] + uu[nt].y + bf2f((unsigned short)(vv[nt].x >> 16));
            float y2 = acc[nt][2] + uu[nt].z + bf2f((unsigned short)(vv[nt].y & 0xffff));
            float y3 = acc[nt][3] + uu[nt].w + bf2f((unsigned short)(vv[nt].y >> 16));
            ssum[nt][0] += y0; ssq[nt][0] += y0 * y0;
            ssum[nt][1] += y1; ssq[nt][1] += y1 * y1;
            ssum[nt][2] += y2; ssq[nt][2] += y2 * y2;
            ssum[nt][3] += y3; ssq[nt][3] += y3 * y3;
            *(uint2*)(yr + nt * 16) = pack4(y0, y1, y2, y3);
        }
        if (g == 0) filt[e] = acc[4][0] + fi + fj;

        e = e2; ie = ie2; je = je2; E0 = E0n; E1 = E1n;
    }

    // stats: reduce over the 16 c-lanes, atomic per feature
    int slot = (blockIdx.x & (SLOTS - 1)) * 128;
    #pragma unroll
    for (int nt = 0; nt < 4; ++nt) {
        #pragma unroll
        for (int q = 0; q < 4; ++q) {
            float S = ssum[nt][q], Q = ssq[nt][q];
            S += __shfl_xor(S, 1, 64); S += __shfl_xor(S, 2, 64);
            S += __shfl_xor(S, 4, 64); S += __shfl_xor(S, 8, 64);
            Q += __shfl_xor(Q, 1, 64); Q += __shfl_xor(Q, 2, 64);
            Q += __shfl_xor(Q, 4, 64); Q += __shfl_xor(Q, 8, 64);
            if (c == 0) {
                int f = nt * 16 + g * 4 + q;
                atomicAdd(&stats[slot + f], S);
                atomicAdd(&stats[slot + 64 + f], Q);
            }
        }
    }
}

// ---------------- per-layer small kernels ----------------

__global__ void k_finbn(const float* __restrict__ stats, float* __restrict__ bnp, float count) {
    int f = threadIdx.x;  // 64 threads
    float S = 0.f, Q = 0.f;
    for (int s = 0; s < SLOTS; ++s) {
        S += stats[s * 128 + f];
        Q += stats[s * 128 + 64 + f];
    }
    float mu = S / count;
    float var = Q / count - mu * mu;
    var = fmaxf(var, 0.f);
    bnp[f] = mu;
    bnp[64 + f] = 1.f / sqrtf(var + EPS);
}

// wave per node; 4 edges x 16 feature-quads in parallel
__global__ __launch_bounds__(256) void k_node_agg(
    const unsigned short* __restrict__ y, const float* __restrict__ filt,
    const int* __restrict__ rowptr, const int* __restrict__ cnt,
    const float* __restrict__ bnp, const float* __restrict__ g1, const float* __restrict__ b1,
    float* __restrict__ agg)
{
    int t = threadIdx.x;
    int lane = t & 63;
    int node = blockIdx.x * 4 + (t >> 6);
    int beg = rowptr[node], end = rowptr[node + 1];
    int es = lane >> 4, fq = lane & 15;
    float4 mu4 = *(const float4*)(bnp + fq * 4);
    float4 rs4 = *(const float4*)(bnp + 64 + fq * 4);
    float4 ga4 = *(const float4*)(g1 + fq * 4);
    float4 be4 = *(const float4*)(b1 + fq * 4);

    float fm = -INFINITY;
    for (int i = beg + lane; i < end; i += 64) fm = fmaxf(fm, filt[i]);
    #pragma unroll
    for (int o = 32; o > 0; o >>= 1) fm = fmaxf(fm, __shfl_xor(fm, o, 64));

    float a0 = 0.f, a1 = 0.f, a2 = 0.f, a3 = 0.f, ss = 0.f;
    #pragma unroll 2
    for (int base = beg; base < end; base += 4) {
        int ee = base + es;
        int eec = min(ee, end - 1);
        float wgt = (ee < end) ? expf(filt[eec] - fm) : 0.f;
        ushort4 yv = *(const ushort4*)(y + (size_t)eec * F + fq * 4);
        float c0 = fmaxf((bf2f(yv.x) - mu4.x) * rs4.x * ga4.x + be4.x, 0.f);
        float c1 = fmaxf((bf2f(yv.y) - mu4.y) * rs4.y * ga4.y + be4.y, 0.f);
        float c2 = fmaxf((bf2f(yv.z) - mu4.z) * rs4.z * ga4.z + be4.z, 0.f);
        float c3 = fmaxf((bf2f(yv.w) - mu4.w) * rs4.w * ga4.w + be4.w, 0.f);
        a0 += wgt * c0; a1 += wgt * c1; a2 += wgt * c2; a3 += wgt * c3;
        ss += wgt;
    }
    #pragma unroll
    for (int o = 16; o <= 32; o <<= 1) {
        a0 += __shfl_xor(a0, o, 64);
        a1 += __shfl_xor(a1, o, 64);
        a2 += __shfl_xor(a2, o, 64);
        a3 += __shfl_xor(a3, o, 64);
        ss += __shfl_xor(ss, o, 64);
    }
    if (lane < 16) {
        float dn = fmaxf((float)cnt[node], 1.f);
        float inv = 1.f / ((ss + 1e-16f) * dn);
        float4 o4;
        o4.x = a0 * inv; o4.y = a1 * inv; o4.z = a2 * inv; o4.w = a3 * inv;
        *(float4*)(agg + (size_t)node * F + fq * 4) = o4;
    }
}

__global__ void k_colstats(const float* __restrict__ agg, float* __restrict__ stats) {
    __shared__ float buf[4][64];
    int t = threadIdx.x;
    int f = t & 63, g = t >> 6;
    float S = 0.f, Q = 0.f;
    for (int n = blockIdx.x * 4 + g; n < N_ATOMS; n += gridDim.x * 4) {
        float v = agg[(size_t)n * F + f];
        S += v; Q += v * v;
    }
    buf[g][f] = S;
    __syncthreads();
    if (t < 64) {
        float s2 = buf[0][t] + buf[1][t] + buf[2][t] + buf[3][t];
        atomicAdd(&stats[(blockIdx.x & 63) * 128 + t], s2);
    }
    __syncthreads();
    buf[g][f] = Q;
    __syncthreads();
    if (t < 64) {
        float q2 = buf[0][t] + buf[1][t] + buf[2][t] + buf[3][t];
        atomicAdd(&stats[(blockIdx.x & 63) * 128 + 64 + t], q2);
    }
}

__global__ void k_node_upd(const float* __restrict__ agg, const float* __restrict__ bnp,
                           const float* __restrict__ g2, const float* __restrict__ b2,
                           const float* __restrict__ xin, float* __restrict__ xout,
                           unsigned short* __restrict__ xbout) {
    int idx = blockIdx.x * 256 + threadIdx.x;
    if (idx < N_ATOMS * F) {
        int f = idx & 63;
        float v = (agg[idx] - bnp[f]) * bnp[64 + f] * g2[f] + b2[f] + xin[idx];
        v = fmaxf(v, 0.f);
        xout[idx] = v;
        xbout[idx] = f2bf(v);
    }
}

// ---------------- head ----------------

__global__ __launch_bounds__(256) void k_head(
    const float* __restrict__ x, const int* __restrict__ target,
    const float* __restrict__ Wfc, const float* __restrict__ bfc,
    const float* __restrict__ Ws, const float* __restrict__ bs,
    float* __restrict__ out)
{
    __shared__ float hbuf[4][64];
    int t = threadIdx.x;
    int lane = t & 63, w = t >> 6;
    int tt = blockIdx.x * 4 + w;
    int a = target[min(tt, T_TGT - 1)];
    float h = fmaxf(x[(size_t)a * F + lane], 0.f);
    hbuf[w][lane] = h;
    __syncthreads();
    float acc = bfc[lane];
    #pragma unroll 8
    for (int k = 0; k < F; ++k) acc += hbuf[w][k] * Wfc[lane * F + k];
    float h2 = fmaxf(acc, 0.f);
    float p0 = h2 * Ws[lane];
    float p1 = h2 * Ws[F + lane];
    #pragma unroll
    for (int o = 32; o > 0; o >>= 1) {
        p0 += __shfl_xor(p0, o, 64);
        p1 += __shfl_xor(p1, o, 64);
    }
    if (lane == 0 && tt < T_TGT) {
        float l0 = p0 + bs[0], l1 = p1 + bs[1];
        float mx = fmaxf(l0, l1);
        float e0v = expf(l0 - mx), e1v = expf(l1 - mx);
        float inv = 1.f / (e0v + e1v);
        out[tt * 2 + 0] = e0v * inv;
        out[tt * 2 + 1] = e1v * inv;
    }
}

// ---------------- launch ----------------

extern "C" void kernel_launch(void* const* d_in, const int* in_sizes, int n_in,
                              void* d_out, int out_size, void* d_ws, size_t ws_size,
                              hipStream_t stream)
{
    const int*   x_types = (const int*)d_in[0];
    const int*   eidx    = (const int*)d_in[1];
    const float* ea      = (const float*)d_in[2];
    const int*   target  = (const int*)d_in[3];
    const float* emb     = (const float*)d_in[4];
    const float* Wc      = (const float*)d_in[5];
    const float* Wf      = (const float*)d_in[7];
    const float* g1      = (const float*)d_in[9];
    const float* b1      = (const float*)d_in[10];
    const float* g2      = (const float*)d_in[11];
    const float* b2      = (const float*)d_in[12];
    const float* Wfc     = (const float*)d_in[13];
    const float* bfc     = (const float*)d_in[14];
    const float* Ws      = (const float*)d_in[15];
    const float* bs      = (const float*)d_in[16];
    float* out = (float*)d_out;
    const int* idx_i = eidx;
    const int* idx_j = eidx + N_EDGES;

    char* p = (char*)d_ws;
    auto alloc = [&](size_t bytes) {
        char* r = p;
        p += (bytes + 255) & ~(size_t)255;
        return r;
    };
    float* xa            = (float*)alloc((size_t)N_ATOMS * F * 4);
    float* xb_f          = (float*)alloc((size_t)N_ATOMS * F * 4);
    unsigned short* x16a = (unsigned short*)alloc((size_t)N_ATOMS * F * 2);
    unsigned short* x16b = (unsigned short*)alloc((size_t)N_ATOMS * F * 2);
    unsigned short* eab  = (unsigned short*)alloc((size_t)N_EDGES * F * 2);
    unsigned short* ybuf = (unsigned short*)alloc((size_t)N_EDGES * F * 2);
    float* filt          = (float*)alloc((size_t)N_EDGES * 4);
    float* ubuf          = (float*)alloc((size_t)N_ATOMS * F * 4);
    unsigned short* vbuf = (unsigned short*)alloc((size_t)N_ATOMS * F * 2);
    float* pi            = (float*)alloc((size_t)N_ATOMS * 4);
    float* pj            = (float*)alloc((size_t)N_ATOMS * 4);
    float* agg           = (float*)alloc((size_t)N_ATOMS * F * 4);
    int* cnt             = (int*)alloc((size_t)N_ATOMS * 4);
    int* rowptr          = (int*)alloc((size_t)(N_ATOMS + 1) * 4);
    int* wofs            = (int*)alloc((size_t)N_ATOMS * 4);
    int* i_s             = (int*)alloc((size_t)N_EDGES * 4);
    int* j_s             = (int*)alloc((size_t)N_EDGES * 4);
    int* einv            = (int*)alloc((size_t)N_EDGES * 4);
    int* bsum            = (int*)alloc(256 * 4);
    float* stats         = (float*)alloc(SLOTS * 128 * 4);
    float* bnp1          = (float*)alloc(128 * 4);
    float* bnp2          = (float*)alloc(128 * 4);
    (void)ws_size; (void)in_sizes; (void)n_in; (void)out_size;

    hipMemsetAsync(cnt, 0, (size_t)N_ATOMS * 4, stream);
    hipMemsetAsync(wofs, 0, (size_t)N_ATOMS * 4, stream);
    k_embed<<<(N_ATOMS * F + 255) / 256, 256, 0, stream>>>(x_types, emb, xa, x16a);
    k_degree<<<(N_EDGES + 255) / 256, 256, 0, stream>>>(idx_i, cnt);
    k_scanA<<<NB_SCAN, 256, 0, stream>>>(cnt, bsum);
    k_scanB<<<1, 256, 0, stream>>>(bsum, rowptr);
    k_scanC<<<NB_SCAN, 256, 0, stream>>>(cnt, bsum, rowptr);
    k_scatter<<<(N_EDGES + 255) / 256, 256, 0, stream>>>(idx_i, idx_j, rowptr, wofs,
                                                         i_s, j_s, einv);
    k_prep2<<<(N_EDGES * 8) / 256, 256, 0, stream>>>(ea, einv, eab);

    float* xcur = xa;
    float* xnxt = xb_f;
    unsigned short* x16cur = x16a;
    unsigned short* x16nxt = x16b;
    for (int l = 0; l < NCONV; ++l) {
        k_node_mm<<<NBLK_N, 256, 0, stream>>>(x16cur,
            Wc + (size_t)l * F * Z, Wf + (size_t)l * Z, ubuf, vbuf, pi, pj);
        hipMemsetAsync(stats, 0, SLOTS * 128 * 4, stream);
        k_edge2<<<NBLK_E, 256, 0, stream>>>(
            eab, ubuf, vbuf, i_s, j_s,
            Wc + (size_t)l * F * Z, Wf + (size_t)l * Z,
            pi, pj,
            ybuf, filt, stats);
        k_finbn<<<1, 64, 0, stream>>>(stats, bnp1, (float)N_EDGES);
        k_node_agg<<<N_ATOMS / 4, 256, 0, stream>>>(ybuf, filt, rowptr, cnt, bnp1,
                                                    g1 + (size_t)l * F, b1 + (size_t)l * F, agg);
        hipMemsetAsync(stats, 0, SLOTS * 128 * 4, stream);
        k_colstats<<<256, 256, 0, stream>>>(agg, stats);
        k_finbn<<<1, 64, 0, stream>>>(stats, bnp2, (float)N_ATOMS);
        k_node_upd<<<(N_ATOMS * F + 255) / 256, 256, 0, stream>>>(
            agg, bnp2, g2 + (size_t)l * F, b2 + (size_t)l * F, xcur, xnxt, x16nxt);
        float* tf = xcur; xcur = xnxt; xnxt = tf;
        unsigned short* ts = x16cur; x16cur = x16nxt; x16nxt = ts;
    }
    k_head<<<T_TGT / 4, 256, 0, stream>>>(xcur, target, Wfc, bfc, Ws, bs, out);
}

// Round 10
// 707.365 us; speedup vs baseline: 1.7548x; 1.7548x over previous
//
#include <hip/hip_runtime.h>
#include <math.h>

#define N_ATOMS 50000
#define N_EDGES 800000
#define F 64
#define Z 192
#define NCONV 3
#define T_TGT 4096
#define EPS 1e-5f
#define SLOTS 64
#define NB_SCAN 196          // ceil(50000/256)
#define NBLK_E 2500          // edge kernel blocks: 2500*64*5 = 800000
#define STEPS_E 5
#define NGRP_N 3125          // 50000/16 node groups
#define NBLK_N 782           // ceil(3125/4)

typedef __attribute__((ext_vector_type(4))) float f32x4;
typedef __attribute__((ext_vector_type(8))) short s16x8;
typedef __attribute__((ext_vector_type(8))) __bf16 bf16x8;

static_assert(NBLK_E * 64 * STEPS_E == N_EDGES, "edge tiling exact");

static __device__ __forceinline__ float bf2f(unsigned short u) {
    return __uint_as_float(((unsigned int)u) << 16);
}
static __device__ __forceinline__ unsigned short f2bf(float f) {
    unsigned int u = __float_as_uint(f);
    unsigned int r = u + 0x7FFFu + ((u >> 16) & 1u);
    return (unsigned short)(r >> 16);
}
static __device__ __forceinline__ bf16x8 pack8(float4 a, float4 b) {
    s16x8 r;
    r[0] = (short)f2bf(a.x); r[1] = (short)f2bf(a.y);
    r[2] = (short)f2bf(a.z); r[3] = (short)f2bf(a.w);
    r[4] = (short)f2bf(b.x); r[5] = (short)f2bf(b.y);
    r[6] = (short)f2bf(b.z); r[7] = (short)f2bf(b.w);
    return __builtin_bit_cast(bf16x8, r);
}
static __device__ __forceinline__ uint2 pack4(float a, float b, float c, float d) {
    uint2 r;
    r.x = (unsigned int)f2bf(a) | ((unsigned int)f2bf(b) << 16);
    r.y = (unsigned int)f2bf(c) | ((unsigned int)f2bf(d) << 16);
    return r;
}

// ---------------- preprocessing ----------------

__global__ void k_embed(const int* __restrict__ types, const float* __restrict__ emb,
                        float* __restrict__ x, unsigned short* __restrict__ xb) {
    int idx = blockIdx.x * 256 + threadIdx.x;
    if (idx < N_ATOMS * F) {
        int n = idx >> 6, f = idx & 63;
        float v = emb[types[n] * F + f];
        x[idx] = v;
        xb[idx] = f2bf(v);
    }
}

__global__ void k_degree(const int* __restrict__ idx_i, int* __restrict__ cnt) {
    int e = blockIdx.x * 256 + threadIdx.x;
    if (e < N_EDGES) atomicAdd(&cnt[idx_i[e]], 1);
}

__global__ void k_scanA(const int* __restrict__ cnt, int* __restrict__ bsum) {
    __shared__ int s[256];
    int base = blockIdx.x * 256, t = threadIdx.x;
    s[t] = (base + t < N_ATOMS) ? cnt[base + t] : 0;
    __syncthreads();
    for (int o = 128; o > 0; o >>= 1) {
        if (t < o) s[t] += s[t + o];
        __syncthreads();
    }
    if (t == 0) bsum[blockIdx.x] = s[0];
}

__global__ void k_scanB(int* __restrict__ bsum, int* __restrict__ rowptr) {
    __shared__ int s[256];
    int t = threadIdx.x;
    int v = (t < NB_SCAN) ? bsum[t] : 0;
    s[t] = v;
    __syncthreads();
    for (int o = 1; o < 256; o <<= 1) {
        int add = (t >= o) ? s[t - o] : 0;
        __syncthreads();
        s[t] += add;
        __syncthreads();
    }
    if (t < NB_SCAN) bsum[t] = s[t] - v;  // exclusive
    if (t == 0) rowptr[N_ATOMS] = N_EDGES;
}

__global__ void k_scanC(const int* __restrict__ cnt, const int* __restrict__ bsum,
                        int* __restrict__ rowptr) {
    __shared__ int s[256];
    int base = blockIdx.x * 256, t = threadIdx.x;
    int v = (base + t < N_ATOMS) ? cnt[base + t] : 0;
    s[t] = v;
    __syncthreads();
    for (int o = 1; o < 256; o <<= 1) {
        int add = (t >= o) ? s[t - o] : 0;
        __syncthreads();
        s[t] += add;
        __syncthreads();
    }
    if (base + t < N_ATOMS) rowptr[base + t] = bsum[blockIdx.x] + s[t] - v;
}

__global__ void k_scatter(const int* __restrict__ idx_i, const int* __restrict__ idx_j,
                          const int* __restrict__ rowptr, int* __restrict__ wofs,
                          int* __restrict__ i_s, int* __restrict__ j_s,
                          int* __restrict__ einv) {
    int e = blockIdx.x * 256 + threadIdx.x;
    if (e < N_EDGES) {
        int i = idx_i[e];
        int pos = rowptr[i] + atomicAdd(&wofs[i], 1);
        i_s[pos] = i;
        j_s[pos] = idx_j[e];
        einv[e] = pos;              // inverse perm: original edge -> CSR slot
    }
}

// edge_attr -> bf16 into CSR slot. 8 lanes per row: reads are wave-contiguous
// (2 KB/wave), each dest 128-B line is covered by ONE store instruction.
__global__ void k_prep2(const float* __restrict__ ea, const int* __restrict__ einv,
                        unsigned short* __restrict__ eab) {
    int idx = blockIdx.x * 256 + threadIdx.x;
    int row = idx >> 3;
    if (row >= N_EDGES) return;
    int seg = (idx & 7) * 8;
    const float* src = ea + (size_t)row * F + seg;
    float4 a = *(const float4*)src;
    float4 b = *(const float4*)(src + 4);
    int pos = einv[row];
    *(bf16x8*)(eab + (size_t)pos * F + seg) = pack8(a, b);
}

// ---------------- per-layer: node projections (MFMA) ----------------
// u[n] = x[n] @ Wc[:,0:64]^T   (fp32)
// v[n] = x[n] @ Wc[:,64:128]^T (bf16)
// pi[n] = x[n].Wf[0:64], pj[n] = x[n].Wf[64:128]
__global__ __launch_bounds__(256) void k_node_mm(
    const unsigned short* __restrict__ xb,
    const float* __restrict__ Wc, const float* __restrict__ Wf,
    float* __restrict__ u, unsigned short* __restrict__ v,
    float* __restrict__ pi, float* __restrict__ pj)
{
    __shared__ unsigned short WL[18 * 64 * 8];   // 9 KB: frag f = kt*9+m
    int t = threadIdx.x;
    int lane = t & 63, w = t >> 6;
    int c = lane & 15, g = lane >> 4;
    int goff = g * 8;

    #pragma unroll
    for (int rep = 0; rep < 5; ++rep) {
        int f = rep * 4 + w;
        if (f < 18) {
            int kt = f / 9, m = f % 9;           // wave-uniform
            bf16x8 val;
            if (m < 8) {
                int colbase = (m < 4) ? 0 : 64;
                const float* wp = Wc + (size_t)((m & 3) * 16 + c) * Z + colbase + kt * 32 + goff;
                val = pack8(*(const float4*)wp, *(const float4*)(wp + 4));
            } else {
                s16x8 zz = {0, 0, 0, 0, 0, 0, 0, 0};
                val = __builtin_bit_cast(bf16x8, zz);
                if (c == 0) {
                    const float* wp = Wf + kt * 32 + goff;
                    val = pack8(*(const float4*)wp, *(const float4*)(wp + 4));
                } else if (c == 1) {
                    const float* wp = Wf + 64 + kt * 32 + goff;
                    val = pack8(*(const float4*)wp, *(const float4*)(wp + 4));
                }
            }
            *(bf16x8*)(WL + ((size_t)f * 64 + lane) * 8) = val;
        }
    }
    __syncthreads();

    int grp = blockIdx.x * 4 + w;
    if (grp >= NGRP_N) return;
    int node = grp * 16 + c;
    const unsigned short* xr = xb + (size_t)node * F;
    bf16x8 X0 = *(const bf16x8*)(xr + goff);
    bf16x8 X1 = *(const bf16x8*)(xr + 32 + goff);

    #define LFR(f) (*(const bf16x8*)(WL + ((size_t)(f) * 64 + lane) * 8))
    f32x4 au[4], av[4], ap = (f32x4){0.f, 0.f, 0.f, 0.f};
    #pragma unroll
    for (int m = 0; m < 4; ++m) {
        au[m] = (f32x4){0.f, 0.f, 0.f, 0.f};
        av[m] = (f32x4){0.f, 0.f, 0.f, 0.f};
        au[m] = __builtin_amdgcn_mfma_f32_16x16x32_bf16(LFR(m), X0, au[m], 0, 0, 0);
        au[m] = __builtin_amdgcn_mfma_f32_16x16x32_bf16(LFR(9 + m), X1, au[m], 0, 0, 0);
        av[m] = __builtin_amdgcn_mfma_f32_16x16x32_bf16(LFR(4 + m), X0, av[m], 0, 0, 0);
        av[m] = __builtin_amdgcn_mfma_f32_16x16x32_bf16(LFR(13 + m), X1, av[m], 0, 0, 0);
    }
    ap = __builtin_amdgcn_mfma_f32_16x16x32_bf16(LFR(8), X0, ap, 0, 0, 0);
    ap = __builtin_amdgcn_mfma_f32_16x16x32_bf16(LFR(17), X1, ap, 0, 0, 0);
    #undef LFR

    float* urow = u + (size_t)node * F + g * 4;
    unsigned short* vrow = v + (size_t)node * F + g * 4;
    #pragma unroll
    for (int m = 0; m < 4; ++m) {
        *(f32x4*)(urow + m * 16) = au[m];
        *(uint2*)(vrow + m * 16) = pack4(av[m][0], av[m][1], av[m][2], av[m][3]);
    }
    if (g == 0) {
        pi[node] = ap[0];
        pj[node] = ap[1];
    }
}

// ---------------- per-layer: edge kernel (streaming K=64 MFMA + row adds) ----------------
// D[row=feat, col=edge]: lane (c,g) owns edge base+c, feats nt*16+g*4+q.
// nt==4 is the filt column: A-rows = (row0: Wf[128:192], rest 0).
// Round-7 proven body: plain loop (compiler unrolls + schedules), (256,3).
__global__ __launch_bounds__(256, 3) void k_edge2(
    const unsigned short* __restrict__ eab,
    const float* __restrict__ u, const unsigned short* __restrict__ v,
    const int* __restrict__ i_s, const int* __restrict__ j_s,
    const float* __restrict__ Wc, const float* __restrict__ Wf,
    const float* __restrict__ pi, const float* __restrict__ pj,
    unsigned short* __restrict__ y, float* __restrict__ filt,
    float* __restrict__ stats)
{
    __shared__ unsigned short WL[10 * 64 * 8];   // 10 frags: f = kt*5+nt
    int t = threadIdx.x;
    int lane = t & 63, w = t >> 6;
    int c = lane & 15, g = lane >> 4;
    int goff = g * 8;

    #pragma unroll
    for (int rep = 0; rep < 3; ++rep) {
        int f = rep * 4 + w;                     // 0..11, wave-uniform
        if (f < 10) {
            int kt = f / 5, nt = f % 5;
            bf16x8 val;
            if (nt < 4) {
                const float* wp = Wc + (size_t)(nt * 16 + c) * Z + 128 + kt * 32 + goff;
                val = pack8(*(const float4*)wp, *(const float4*)(wp + 4));
            } else {
                s16x8 zz = {0, 0, 0, 0, 0, 0, 0, 0};
                val = __builtin_bit_cast(bf16x8, zz);
                if (c == 0) {
                    const float* wp = Wf + 128 + kt * 32 + goff;
                    val = pack8(*(const float4*)wp, *(const float4*)(wp + 4));
                }
            }
            *(bf16x8*)(WL + ((size_t)f * 64 + lane) * 8) = val;
        }
    }
    __syncthreads();

    bf16x8 A[2][5];
    #pragma unroll
    for (int kt = 0; kt < 2; ++kt)
        #pragma unroll
        for (int nt = 0; nt < 5; ++nt)
            A[kt][nt] = *(const bf16x8*)(WL + ((size_t)(kt * 5 + nt) * 64 + lane) * 8);

    float ssum[4][4] = {{0.f}}, ssq[4][4] = {{0.f}};

    int e = blockIdx.x * (STEPS_E * 64) + w * 16 + c;
    int ie = i_s[e], je = j_s[e];
    bf16x8 E0 = *(const bf16x8*)(eab + (size_t)e * F + goff);
    bf16x8 E1 = *(const bf16x8*)(eab + (size_t)e * F + 32 + goff);

    for (int s = 0; s < STEPS_E; ++s) {
        // u/v row loads for current edge (addresses ready since last iter)
        const float* ur = u + (size_t)ie * F + g * 4;
        const unsigned short* vr = v + (size_t)je * F + g * 4;
        float4 uu[4];
        uint2 vv[4];
        #pragma unroll
        for (int nt = 0; nt < 4; ++nt) {
            uu[nt] = *(const float4*)(ur + nt * 16);
            vv[nt] = *(const uint2*)(vr + nt * 16);
        }
        float fi = 0.f, fj = 0.f;
        if (g == 0) { fi = pi[ie]; fj = pj[je]; }

        // prefetch next step
        int e2 = e, ie2 = ie, je2 = je;
        bf16x8 E0n = E0, E1n = E1;
        if (s + 1 < STEPS_E) {
            e2 = e + 64;
            ie2 = i_s[e2];
            je2 = j_s[e2];
            E0n = *(const bf16x8*)(eab + (size_t)e2 * F + goff);
            E1n = *(const bf16x8*)(eab + (size_t)e2 * F + 32 + goff);
        }

        f32x4 acc[5];
        #pragma unroll
        for (int nt = 0; nt < 5; ++nt) {
            acc[nt] = (f32x4){0.f, 0.f, 0.f, 0.f};
            acc[nt] = __builtin_amdgcn_mfma_f32_16x16x32_bf16(A[0][nt], E0, acc[nt], 0, 0, 0);
            acc[nt] = __builtin_amdgcn_mfma_f32_16x16x32_bf16(A[1][nt], E1, acc[nt], 0, 0, 0);
        }

        unsigned short* yr = y + (size_t)e * F + g * 4;
        #pragma unroll
        for (int nt = 0; nt < 4; ++nt) {
            float y0 = acc[nt][0] + uu[nt].x + bf2f((unsigned short)(vv[nt].x & 0xffff));
            float y1 = acc[nt][1] + uu[nt].y + bf2f((unsigned short)(vv[nt].x >> 16));
            float y2 = acc[nt][2] + uu[nt].z + bf2f((unsigned short)(vv[nt].y & 0xffff));
            float y3 = acc[nt][3] + uu[nt].w + bf2f((unsigned short)(vv[nt].y >> 16));
            ssum[nt][0] += y0; ssq[nt][0] += y0 * y0;
            ssum[nt][1] += y1; ssq[nt][1] += y1 * y1;
            ssum[nt][2] += y2; ssq[nt][2] += y2 * y2;
            ssum[nt][3] += y3; ssq[nt][3] += y3 * y3;
            *(uint2*)(yr + nt * 16) = pack4(y0, y1, y2, y3);
        }
        if (g == 0) filt[e] = acc[4][0] + fi + fj;

        e = e2; ie = ie2; je = je2; E0 = E0n; E1 = E1n;
    }

    // stats: reduce over the 16 c-lanes, atomic per feature
    int slot = (blockIdx.x & (SLOTS - 1)) * 128;
    #pragma unroll
    for (int nt = 0; nt < 4; ++nt) {
        #pragma unroll
        for (int q = 0; q < 4; ++q) {
            float S = ssum[nt][q], Q = ssq[nt][q];
            S += __shfl_xor(S, 1, 64); S += __shfl_xor(S, 2, 64);
            S += __shfl_xor(S, 4, 64); S += __shfl_xor(S, 8, 64);
            Q += __shfl_xor(Q, 1, 64); Q += __shfl_xor(Q, 2, 64);
            Q += __shfl_xor(Q, 4, 64); Q += __shfl_xor(Q, 8, 64);
            if (c == 0) {
                int f = nt * 16 + g * 4 + q;
                atomicAdd(&stats[slot + f], S);
                atomicAdd(&stats[slot + 64 + f], Q);
            }
        }
    }
}

// ---------------- per-layer small kernels ----------------

// Reads stats -> bnp, then ZEROES stats (replaces per-layer hipMemsetAsync).
__global__ void k_finbn(float* __restrict__ stats, float* __restrict__ bnp, float count) {
    int f = threadIdx.x;  // 64 threads
    float S = 0.f, Q = 0.f;
    for (int s = 0; s < SLOTS; ++s) {
        S += stats[s * 128 + f];
        Q += stats[s * 128 + 64 + f];
    }
    for (int s = 0; s < SLOTS; ++s) {
        stats[s * 128 + f] = 0.f;
        stats[s * 128 + 64 + f] = 0.f;
    }
    float mu = S / count;
    float var = Q / count - mu * mu;
    var = fmaxf(var, 0.f);
    bnp[f] = mu;
    bnp[64 + f] = 1.f / sqrtf(var + EPS);
}

// wave per node; 4 edges x 16 feature-quads in parallel
__global__ __launch_bounds__(256) void k_node_agg(
    const unsigned short* __restrict__ y, const float* __restrict__ filt,
    const int* __restrict__ rowptr, const int* __restrict__ cnt,
    const float* __restrict__ bnp, const float* __restrict__ g1, const float* __restrict__ b1,
    float* __restrict__ agg)
{
    int t = threadIdx.x;
    int lane = t & 63;
    int node = blockIdx.x * 4 + (t >> 6);
    int beg = rowptr[node], end = rowptr[node + 1];
    int es = lane >> 4, fq = lane & 15;
    float4 mu4 = *(const float4*)(bnp + fq * 4);
    float4 rs4 = *(const float4*)(bnp + 64 + fq * 4);
    float4 ga4 = *(const float4*)(g1 + fq * 4);
    float4 be4 = *(const float4*)(b1 + fq * 4);

    float fm = -INFINITY;
    for (int i = beg + lane; i < end; i += 64) fm = fmaxf(fm, filt[i]);
    #pragma unroll
    for (int o = 32; o > 0; o >>= 1) fm = fmaxf(fm, __shfl_xor(fm, o, 64));

    float a0 = 0.f, a1 = 0.f, a2 = 0.f, a3 = 0.f, ss = 0.f;
    #pragma unroll 2
    for (int base = beg; base < end; base += 4) {
        int ee = base + es;
        int eec = min(ee, end - 1);
        float wgt = (ee < end) ? expf(filt[eec] - fm) : 0.f;
        ushort4 yv = *(const ushort4*)(y + (size_t)eec * F + fq * 4);
        float c0 = fmaxf((bf2f(yv.x) - mu4.x) * rs4.x * ga4.x + be4.x, 0.f);
        float c1 = fmaxf((bf2f(yv.y) - mu4.y) * rs4.y * ga4.y + be4.y, 0.f);
        float c2 = fmaxf((bf2f(yv.z) - mu4.z) * rs4.z * ga4.z + be4.z, 0.f);
        float c3 = fmaxf((bf2f(yv.w) - mu4.w) * rs4.w * ga4.w + be4.w, 0.f);
        a0 += wgt * c0; a1 += wgt * c1; a2 += wgt * c2; a3 += wgt * c3;
        ss += wgt;
    }
    #pragma unroll
    for (int o = 16; o <= 32; o <<= 1) {
        a0 += __shfl_xor(a0, o, 64);
        a1 += __shfl_xor(a1, o, 64);
        a2 += __shfl_xor(a2, o, 64);
        a3 += __shfl_xor(a3, o, 64);
        ss += __shfl_xor(ss, o, 64);
    }
    if (lane < 16) {
        float dn = fmaxf((float)cnt[node], 1.f);
        float inv = 1.f / ((ss + 1e-16f) * dn);
        float4 o4;
        o4.x = a0 * inv; o4.y = a1 * inv; o4.z = a2 * inv; o4.w = a3 * inv;
        *(float4*)(agg + (size_t)node * F + fq * 4) = o4;
    }
}

__global__ void k_colstats(const float* __restrict__ agg, float* __restrict__ stats) {
    __shared__ float buf[4][64];
    int t = threadIdx.x;
    int f = t & 63, g = t >> 6;
    float S = 0.f, Q = 0.f;
    for (int n = blockIdx.x * 4 + g; n < N_ATOMS; n += gridDim.x * 4) {
        float v = agg[(size_t)n * F + f];
        S += v; Q += v * v;
    }
    buf[g][f] = S;
    __syncthreads();
    if (t < 64) {
        float s2 = buf[0][t] + buf[1][t] + buf[2][t] + buf[3][t];
        atomicAdd(&stats[(blockIdx.x & 63) * 128 + t], s2);
    }
    __syncthreads();
    buf[g][f] = Q;
    __syncthreads();
    if (t < 64) {
        float q2 = buf[0][t] + buf[1][t] + buf[2][t] + buf[3][t];
        atomicAdd(&stats[(blockIdx.x & 63) * 128 + 64 + t], q2);
    }
}

__global__ void k_node_upd(const float* __restrict__ agg, const float* __restrict__ bnp,
                           const float* __restrict__ g2, const float* __restrict__ b2,
                           const float* __restrict__ xin, float* __restrict__ xout,
                           unsigned short* __restrict__ xbout) {
    int idx = blockIdx.x * 256 + threadIdx.x;
    if (idx < N_ATOMS * F) {
        int f = idx & 63;
        float v = (agg[idx] - bnp[f]) * bnp[64 + f] * g2[f] + b2[f] + xin[idx];
        v = fmaxf(v, 0.f);
        xout[idx] = v;
        xbout[idx] = f2bf(v);
    }
}

// ---------------- head ----------------

__global__ __launch_bounds__(256) void k_head(
    const float* __restrict__ x, const int* __restrict__ target,
    const float* __restrict__ Wfc, const float* __restrict__ bfc,
    const float* __restrict__ Ws, const float* __restrict__ bs,
    float* __restrict__ out)
{
    __shared__ float hbuf[4][64];
    int t = threadIdx.x;
    int lane = t & 63, w = t >> 6;
    int tt = blockIdx.x * 4 + w;
    int a = target[min(tt, T_TGT - 1)];
    float h = fmaxf(x[(size_t)a * F + lane], 0.f);
    hbuf[w][lane] = h;
    __syncthreads();
    float acc = bfc[lane];
    #pragma unroll 8
    for (int k = 0; k < F; ++k) acc += hbuf[w][k] * Wfc[lane * F + k];
    float h2 = fmaxf(acc, 0.f);
    float p0 = h2 * Ws[lane];
    float p1 = h2 * Ws[F + lane];
    #pragma unroll
    for (int o = 32; o > 0; o >>= 1) {
        p0 += __shfl_xor(p0, o, 64);
        p1 += __shfl_xor(p1, o, 64);
    }
    if (lane == 0 && tt < T_TGT) {
        float l0 = p0 + bs[0], l1 = p1 + bs[1];
        float mx = fmaxf(l0, l1);
        float e0v = expf(l0 - mx), e1v = expf(l1 - mx);
        float inv = 1.f / (e0v + e1v);
        out[tt * 2 + 0] = e0v * inv;
        out[tt * 2 + 1] = e1v * inv;
    }
}

// ---------------- launch ----------------

extern "C" void kernel_launch(void* const* d_in, const int* in_sizes, int n_in,
                              void* d_out, int out_size, void* d_ws, size_t ws_size,
                              hipStream_t stream)
{
    const int*   x_types = (const int*)d_in[0];
    const int*   eidx    = (const int*)d_in[1];
    const float* ea      = (const float*)d_in[2];
    const int*   target  = (const int*)d_in[3];
    const float* emb     = (const float*)d_in[4];
    const float* Wc      = (const float*)d_in[5];
    const float* Wf      = (const float*)d_in[7];
    const float* g1      = (const float*)d_in[9];
    const float* b1      = (const float*)d_in[10];
    const float* g2      = (const float*)d_in[11];
    const float* b2      = (const float*)d_in[12];
    const float* Wfc     = (const float*)d_in[13];
    const float* bfc     = (const float*)d_in[14];
    const float* Ws      = (const float*)d_in[15];
    const float* bs      = (const float*)d_in[16];
    float* out = (float*)d_out;
    const int* idx_i = eidx;
    const int* idx_j = eidx + N_EDGES;

    char* p = (char*)d_ws;
    auto alloc = [&](size_t bytes) {
        char* r = p;
        p += (bytes + 255) & ~(size_t)255;
        return r;
    };
    float* xa            = (float*)alloc((size_t)N_ATOMS * F * 4);
    float* xb_f          = (float*)alloc((size_t)N_ATOMS * F * 4);
    unsigned short* x16a = (unsigned short*)alloc((size_t)N_ATOMS * F * 2);
    unsigned short* x16b = (unsigned short*)alloc((size_t)N_ATOMS * F * 2);
    unsigned short* eab  = (unsigned short*)alloc((size_t)N_EDGES * F * 2);
    unsigned short* ybuf = (unsigned short*)alloc((size_t)N_EDGES * F * 2);
    float* filt          = (float*)alloc((size_t)N_EDGES * 4);
    float* ubuf          = (float*)alloc((size_t)N_ATOMS * F * 4);
    unsigned short* vbuf = (unsigned short*)alloc((size_t)N_ATOMS * F * 2);
    float* pi            = (float*)alloc((size_t)N_ATOMS * 4);
    float* pj            = (float*)alloc((size_t)N_ATOMS * 4);
    float* agg           = (float*)alloc((size_t)N_ATOMS * F * 4);
    int* cnt             = (int*)alloc((size_t)N_ATOMS * 4);
    int* rowptr          = (int*)alloc((size_t)(N_ATOMS + 1) * 4);
    int* wofs            = (int*)alloc((size_t)N_ATOMS * 4);
    int* i_s             = (int*)alloc((size_t)N_EDGES * 4);
    int* j_s             = (int*)alloc((size_t)N_EDGES * 4);
    int* einv            = (int*)alloc((size_t)N_EDGES * 4);
    int* bsum            = (int*)alloc(256 * 4);
    float* stats         = (float*)alloc(SLOTS * 128 * 4);
    float* bnp1          = (float*)alloc(128 * 4);
    float* bnp2          = (float*)alloc(128 * 4);
    (void)ws_size; (void)in_sizes; (void)n_in; (void)out_size;

    hipMemsetAsync(cnt, 0, (size_t)N_ATOMS * 4, stream);
    hipMemsetAsync(wofs, 0, (size_t)N_ATOMS * 4, stream);
    hipMemsetAsync(stats, 0, SLOTS * 128 * 4, stream);   // k_finbn re-zeroes thereafter
    k_embed<<<(N_ATOMS * F + 255) / 256, 256, 0, stream>>>(x_types, emb, xa, x16a);
    k_degree<<<(N_EDGES + 255) / 256, 256, 0, stream>>>(idx_i, cnt);
    k_scanA<<<NB_SCAN, 256, 0, stream>>>(cnt, bsum);
    k_scanB<<<1, 256, 0, stream>>>(bsum, rowptr);
    k_scanC<<<NB_SCAN, 256, 0, stream>>>(cnt, bsum, rowptr);
    k_scatter<<<(N_EDGES + 255) / 256, 256, 0, stream>>>(idx_i, idx_j, rowptr, wofs,
                                                         i_s, j_s, einv);
    k_prep2<<<(N_EDGES * 8) / 256, 256, 0, stream>>>(ea, einv, eab);

    float* xcur = xa;
    float* xnxt = xb_f;
    unsigned short* x16cur = x16a;
    unsigned short* x16nxt = x16b;
    for (int l = 0; l < NCONV; ++l) {
        k_node_mm<<<NBLK_N, 256, 0, stream>>>(x16cur,
            Wc + (size_t)l * F * Z, Wf + (size_t)l * Z, ubuf, vbuf, pi, pj);
        k_edge2<<<NBLK_E, 256, 0, stream>>>(
            eab, ubuf, vbuf, i_s, j_s,
            Wc + (size_t)l * F * Z, Wf + (size_t)l * Z,
            pi, pj,
            ybuf, filt, stats);
        k_finbn<<<1, 64, 0, stream>>>(stats, bnp1, (float)N_EDGES);
        k_node_agg<<<N_ATOMS / 4, 256, 0, stream>>>(ybuf, filt, rowptr, cnt, bnp1,
                                                    g1 + (size_t)l * F, b1 + (size_t)l * F, agg);
        k_colstats<<<256, 256, 0, stream>>>(agg, stats);
        k_finbn<<<1, 64, 0, stream>>>(stats, bnp2, (float)N_ATOMS);
        k_node_upd<<<(N_ATOMS * F + 255) / 256, 256, 0, stream>>>(
            agg, bnp2, g2 + (size_t)l * F, b2 + (size_t)l * F, xcur, xnxt, x16nxt);
        float* tf = xcur; xcur = xnxt; xnxt = tf;
        unsigned short* ts = x16cur; x16cur = x16nxt; x16nxt = ts;
    }
    k_head<<<T_TGT / 4, 256, 0, stream>>>(xcur, target, Wfc, bfc, Ws, bs, out);
}

// Round 11
// 698.961 us; speedup vs baseline: 1.7759x; 1.0120x over previous
//
#include <hip/hip_runtime.h>
#include <math.h>

#define N_ATOMS 50000
#define N_EDGES 800000
#define F 64
#define Z 192
#define NCONV 3
#define T_TGT 4096
#define EPS 1e-5f
#define SLOTS 128
#define NB_SCAN 196          // ceil(50000/256)
#define NBLK_E 2500          // edge kernel blocks: 2500*64*5 = 800000
#define STEPS_E 5
#define NGRP_N 3125          // 50000/16 node groups
#define NBLK_N 782           // ceil(3125/4)

typedef __attribute__((ext_vector_type(4))) float f32x4;
typedef __attribute__((ext_vector_type(8))) short s16x8;
typedef __attribute__((ext_vector_type(8))) __bf16 bf16x8;

static_assert(NBLK_E * 64 * STEPS_E == N_EDGES, "edge tiling exact");

static __device__ __forceinline__ float bf2f(unsigned short u) {
    return __uint_as_float(((unsigned int)u) << 16);
}
static __device__ __forceinline__ unsigned short f2bf(float f) {
    unsigned int u = __float_as_uint(f);
    unsigned int r = u + 0x7FFFu + ((u >> 16) & 1u);
    return (unsigned short)(r >> 16);
}
static __device__ __forceinline__ bf16x8 pack8(float4 a, float4 b) {
    s16x8 r;
    r[0] = (short)f2bf(a.x); r[1] = (short)f2bf(a.y);
    r[2] = (short)f2bf(a.z); r[3] = (short)f2bf(a.w);
    r[4] = (short)f2bf(b.x); r[5] = (short)f2bf(b.y);
    r[6] = (short)f2bf(b.z); r[7] = (short)f2bf(b.w);
    return __builtin_bit_cast(bf16x8, r);
}
static __device__ __forceinline__ uint2 pack4(float a, float b, float c, float d) {
    uint2 r;
    r.x = (unsigned int)f2bf(a) | ((unsigned int)f2bf(b) << 16);
    r.y = (unsigned int)f2bf(c) | ((unsigned int)f2bf(d) << 16);
    return r;
}

// ---------------- preprocessing ----------------

__global__ void k_embed(const int* __restrict__ types, const float* __restrict__ emb,
                        float* __restrict__ x, unsigned short* __restrict__ xb) {
    int idx = blockIdx.x * 256 + threadIdx.x;
    if (idx < N_ATOMS * F) {
        int n = idx >> 6, f = idx & 63;
        float v = emb[types[n] * F + f];
        x[idx] = v;
        xb[idx] = f2bf(v);
    }
}

__global__ void k_degree(const int* __restrict__ idx_i, int* __restrict__ cnt) {
    int e = blockIdx.x * 256 + threadIdx.x;
    if (e < N_EDGES) atomicAdd(&cnt[idx_i[e]], 1);
}

__global__ void k_scanA(const int* __restrict__ cnt, int* __restrict__ bsum) {
    __shared__ int s[256];
    int base = blockIdx.x * 256, t = threadIdx.x;
    s[t] = (base + t < N_ATOMS) ? cnt[base + t] : 0;
    __syncthreads();
    for (int o = 128; o > 0; o >>= 1) {
        if (t < o) s[t] += s[t + o];
        __syncthreads();
    }
    if (t == 0) bsum[blockIdx.x] = s[0];
}

__global__ void k_scanB(int* __restrict__ bsum, int* __restrict__ rowptr) {
    __shared__ int s[256];
    int t = threadIdx.x;
    int v = (t < NB_SCAN) ? bsum[t] : 0;
    s[t] = v;
    __syncthreads();
    for (int o = 1; o < 256; o <<= 1) {
        int add = (t >= o) ? s[t - o] : 0;
        __syncthreads();
        s[t] += add;
        __syncthreads();
    }
    if (t < NB_SCAN) bsum[t] = s[t] - v;  // exclusive
    if (t == 0) rowptr[N_ATOMS] = N_EDGES;
}

__global__ void k_scanC(const int* __restrict__ cnt, const int* __restrict__ bsum,
                        int* __restrict__ rowptr) {
    __shared__ int s[256];
    int base = blockIdx.x * 256, t = threadIdx.x;
    int v = (base + t < N_ATOMS) ? cnt[base + t] : 0;
    s[t] = v;
    __syncthreads();
    for (int o = 1; o < 256; o <<= 1) {
        int add = (t >= o) ? s[t - o] : 0;
        __syncthreads();
        s[t] += add;
        __syncthreads();
    }
    if (base + t < N_ATOMS) rowptr[base + t] = bsum[blockIdx.x] + s[t] - v;
}

__global__ void k_scatter(const int* __restrict__ idx_i, const int* __restrict__ idx_j,
                          const int* __restrict__ rowptr, int* __restrict__ wofs,
                          int* __restrict__ i_s, int* __restrict__ j_s,
                          int* __restrict__ einv) {
    int e = blockIdx.x * 256 + threadIdx.x;
    if (e < N_EDGES) {
        int i = idx_i[e];
        int pos = rowptr[i] + atomicAdd(&wofs[i], 1);
        i_s[pos] = i;
        j_s[pos] = idx_j[e];
        einv[e] = pos;              // inverse perm: original edge -> CSR slot
    }
}

// edge_attr -> bf16 into CSR slot. 8 lanes per row: reads are wave-contiguous
// (2 KB/wave), each dest 128-B line is covered by ONE store instruction.
__global__ void k_prep2(const float* __restrict__ ea, const int* __restrict__ einv,
                        unsigned short* __restrict__ eab) {
    int idx = blockIdx.x * 256 + threadIdx.x;
    int row = idx >> 3;
    if (row >= N_EDGES) return;
    int seg = (idx & 7) * 8;
    const float* src = ea + (size_t)row * F + seg;
    float4 a = *(const float4*)src;
    float4 b = *(const float4*)(src + 4);
    int pos = einv[row];
    *(bf16x8*)(eab + (size_t)pos * F + seg) = pack8(a, b);
}

// ---------------- per-layer: node projections (MFMA) ----------------
// u[n] = x[n] @ Wc[:,0:64]^T   (fp32)
// v[n] = x[n] @ Wc[:,64:128]^T (bf16)
// pi[n] = x[n].Wf[0:64], pj[n] = x[n].Wf[64:128]
__global__ __launch_bounds__(256) void k_node_mm(
    const unsigned short* __restrict__ xb,
    const float* __restrict__ Wc, const float* __restrict__ Wf,
    float* __restrict__ u, unsigned short* __restrict__ v,
    float* __restrict__ pi, float* __restrict__ pj)
{
    __shared__ unsigned short WL[18 * 64 * 8];   // 9 KB: frag f = kt*9+m
    int t = threadIdx.x;
    int lane = t & 63, w = t >> 6;
    int c = lane & 15, g = lane >> 4;
    int goff = g * 8;

    #pragma unroll
    for (int rep = 0; rep < 5; ++rep) {
        int f = rep * 4 + w;
        if (f < 18) {
            int kt = f / 9, m = f % 9;           // wave-uniform
            bf16x8 val;
            if (m < 8) {
                int colbase = (m < 4) ? 0 : 64;
                const float* wp = Wc + (size_t)((m & 3) * 16 + c) * Z + colbase + kt * 32 + goff;
                val = pack8(*(const float4*)wp, *(const float4*)(wp + 4));
            } else {
                s16x8 zz = {0, 0, 0, 0, 0, 0, 0, 0};
                val = __builtin_bit_cast(bf16x8, zz);
                if (c == 0) {
                    const float* wp = Wf + kt * 32 + goff;
                    val = pack8(*(const float4*)wp, *(const float4*)(wp + 4));
                } else if (c == 1) {
                    const float* wp = Wf + 64 + kt * 32 + goff;
                    val = pack8(*(const float4*)wp, *(const float4*)(wp + 4));
                }
            }
            *(bf16x8*)(WL + ((size_t)f * 64 + lane) * 8) = val;
        }
    }
    __syncthreads();

    int grp = blockIdx.x * 4 + w;
    if (grp >= NGRP_N) return;
    int node = grp * 16 + c;
    const unsigned short* xr = xb + (size_t)node * F;
    bf16x8 X0 = *(const bf16x8*)(xr + goff);
    bf16x8 X1 = *(const bf16x8*)(xr + 32 + goff);

    #define LFR(f) (*(const bf16x8*)(WL + ((size_t)(f) * 64 + lane) * 8))
    f32x4 au[4], av[4], ap = (f32x4){0.f, 0.f, 0.f, 0.f};
    #pragma unroll
    for (int m = 0; m < 4; ++m) {
        au[m] = (f32x4){0.f, 0.f, 0.f, 0.f};
        av[m] = (f32x4){0.f, 0.f, 0.f, 0.f};
        au[m] = __builtin_amdgcn_mfma_f32_16x16x32_bf16(LFR(m), X0, au[m], 0, 0, 0);
        au[m] = __builtin_amdgcn_mfma_f32_16x16x32_bf16(LFR(9 + m), X1, au[m], 0, 0, 0);
        av[m] = __builtin_amdgcn_mfma_f32_16x16x32_bf16(LFR(4 + m), X0, av[m], 0, 0, 0);
        av[m] = __builtin_amdgcn_mfma_f32_16x16x32_bf16(LFR(13 + m), X1, av[m], 0, 0, 0);
    }
    ap = __builtin_amdgcn_mfma_f32_16x16x32_bf16(LFR(8), X0, ap, 0, 0, 0);
    ap = __builtin_amdgcn_mfma_f32_16x16x32_bf16(LFR(17), X1, ap, 0, 0, 0);
    #undef LFR

    float* urow = u + (size_t)node * F + g * 4;
    unsigned short* vrow = v + (size_t)node * F + g * 4;
    #pragma unroll
    for (int m = 0; m < 4; ++m) {
        *(f32x4*)(urow + m * 16) = au[m];
        *(uint2*)(vrow + m * 16) = pack4(av[m][0], av[m][1], av[m][2], av[m][3]);
    }
    if (g == 0) {
        pi[node] = ap[0];
        pj[node] = ap[1];
    }
}

// ---------------- per-layer: edge kernel (streaming K=64 MFMA + row adds) ----------------
// D[row=feat, col=edge]: lane (c,g) owns edge base+c, feats nt*16+g*4+q.
// nt==4 is the filt column: A-rows = (row0: Wf[128:192], rest 0).
// Round-7 proven body: plain loop (compiler unrolls + schedules), (256,3).
__global__ __launch_bounds__(256, 3) void k_edge2(
    const unsigned short* __restrict__ eab,
    const float* __restrict__ u, const unsigned short* __restrict__ v,
    const int* __restrict__ i_s, const int* __restrict__ j_s,
    const float* __restrict__ Wc, const float* __restrict__ Wf,
    const float* __restrict__ pi, const float* __restrict__ pj,
    unsigned short* __restrict__ y, float* __restrict__ filt,
    float* __restrict__ stats)
{
    __shared__ unsigned short WL[10 * 64 * 8];   // 10 frags: f = kt*5+nt
    int t = threadIdx.x;
    int lane = t & 63, w = t >> 6;
    int c = lane & 15, g = lane >> 4;
    int goff = g * 8;

    #pragma unroll
    for (int rep = 0; rep < 3; ++rep) {
        int f = rep * 4 + w;                     // 0..11, wave-uniform
        if (f < 10) {
            int kt = f / 5, nt = f % 5;
            bf16x8 val;
            if (nt < 4) {
                const float* wp = Wc + (size_t)(nt * 16 + c) * Z + 128 + kt * 32 + goff;
                val = pack8(*(const float4*)wp, *(const float4*)(wp + 4));
            } else {
                s16x8 zz = {0, 0, 0, 0, 0, 0, 0, 0};
                val = __builtin_bit_cast(bf16x8, zz);
                if (c == 0) {
                    const float* wp = Wf + 128 + kt * 32 + goff;
                    val = pack8(*(const float4*)wp, *(const float4*)(wp + 4));
                }
            }
            *(bf16x8*)(WL + ((size_t)f * 64 + lane) * 8) = val;
        }
    }
    __syncthreads();

    bf16x8 A[2][5];
    #pragma unroll
    for (int kt = 0; kt < 2; ++kt)
        #pragma unroll
        for (int nt = 0; nt < 5; ++nt)
            A[kt][nt] = *(const bf16x8*)(WL + ((size_t)(kt * 5 + nt) * 64 + lane) * 8);

    float ssum[4][4] = {{0.f}}, ssq[4][4] = {{0.f}};

    int e = blockIdx.x * (STEPS_E * 64) + w * 16 + c;
    int ie = i_s[e], je = j_s[e];
    bf16x8 E0 = *(const bf16x8*)(eab + (size_t)e * F + goff);
    bf16x8 E1 = *(const bf16x8*)(eab + (size_t)e * F + 32 + goff);

    for (int s = 0; s < STEPS_E; ++s) {
        // u/v row loads for current edge (addresses ready since last iter)
        const float* ur = u + (size_t)ie * F + g * 4;
        const unsigned short* vr = v + (size_t)je * F + g * 4;
        float4 uu[4];
        uint2 vv[4];
        #pragma unroll
        for (int nt = 0; nt < 4; ++nt) {
            uu[nt] = *(const float4*)(ur + nt * 16);
            vv[nt] = *(const uint2*)(vr + nt * 16);
        }
        float fi = 0.f, fj = 0.f;
        if (g == 0) { fi = pi[ie]; fj = pj[je]; }

        // prefetch next step
        int e2 = e, ie2 = ie, je2 = je;
        bf16x8 E0n = E0, E1n = E1;
        if (s + 1 < STEPS_E) {
            e2 = e + 64;
            ie2 = i_s[e2];
            je2 = j_s[e2];
            E0n = *(const bf16x8*)(eab + (size_t)e2 * F + goff);
            E1n = *(const bf16x8*)(eab + (size_t)e2 * F + 32 + goff);
        }

        f32x4 acc[5];
        #pragma unroll
        for (int nt = 0; nt < 5; ++nt) {
            acc[nt] = (f32x4){0.f, 0.f, 0.f, 0.f};
            acc[nt] = __builtin_amdgcn_mfma_f32_16x16x32_bf16(A[0][nt], E0, acc[nt], 0, 0, 0);
            acc[nt] = __builtin_amdgcn_mfma_f32_16x16x32_bf16(A[1][nt], E1, acc[nt], 0, 0, 0);
        }

        unsigned short* yr = y + (size_t)e * F + g * 4;
        #pragma unroll
        for (int nt = 0; nt < 4; ++nt) {
            float y0 = acc[nt][0] + uu[nt].x + bf2f((unsigned short)(vv[nt].x & 0xffff));
            float y1 = acc[nt][1] + uu[nt].y + bf2f((unsigned short)(vv[nt].x >> 16));
            float y2 = acc[nt][2] + uu[nt].z + bf2f((unsigned short)(vv[nt].y & 0xffff));
            float y3 = acc[nt][3] + uu[nt].w + bf2f((unsigned short)(vv[nt].y >> 16));
            ssum[nt][0] += y0; ssq[nt][0] += y0 * y0;
            ssum[nt][1] += y1; ssq[nt][1] += y1 * y1;
            ssum[nt][2] += y2; ssq[nt][2] += y2 * y2;
            ssum[nt][3] += y3; ssq[nt][3] += y3 * y3;
            *(uint2*)(yr + nt * 16) = pack4(y0, y1, y2, y3);
        }
        if (g == 0) filt[e] = acc[4][0] + fi + fj;

        e = e2; ie = ie2; je = je2; E0 = E0n; E1 = E1n;
    }

    // stats: reduce over the 16 c-lanes, atomic per feature
    int slot = (blockIdx.x & (SLOTS - 1)) * 128;
    #pragma unroll
    for (int nt = 0; nt < 4; ++nt) {
        #pragma unroll
        for (int q = 0; q < 4; ++q) {
            float S = ssum[nt][q], Q = ssq[nt][q];
            S += __shfl_xor(S, 1, 64); S += __shfl_xor(S, 2, 64);
            S += __shfl_xor(S, 4, 64); S += __shfl_xor(S, 8, 64);
            Q += __shfl_xor(Q, 1, 64); Q += __shfl_xor(Q, 2, 64);
            Q += __shfl_xor(Q, 4, 64); Q += __shfl_xor(Q, 8, 64);
            if (c == 0) {
                int f = nt * 16 + g * 4 + q;
                atomicAdd(&stats[slot + f], S);
                atomicAdd(&stats[slot + 64 + f], Q);
            }
        }
    }
}

// ---------------- per-layer small kernels ----------------

// Reads stats -> bnp, then ZEROES stats (replaces per-layer hipMemsetAsync).
__global__ void k_finbn(float* __restrict__ stats, float* __restrict__ bnp, float count) {
    int f = threadIdx.x;  // 64 threads
    float S = 0.f, Q = 0.f;
    for (int s = 0; s < SLOTS; ++s) {
        S += stats[s * 128 + f];
        Q += stats[s * 128 + 64 + f];
    }
    for (int s = 0; s < SLOTS; ++s) {
        stats[s * 128 + f] = 0.f;
        stats[s * 128 + 64 + f] = 0.f;
    }
    float mu = S / count;
    float var = Q / count - mu * mu;
    var = fmaxf(var, 0.f);
    bnp[f] = mu;
    bnp[64 + f] = 1.f / sqrtf(var + EPS);
}

// wave per node; 4 edges x 16 feature-quads in parallel.
// Fused BN2 stats: block-reduced agg sum/sumsq -> slot-replicated atomics.
__global__ __launch_bounds__(256) void k_node_agg(
    const unsigned short* __restrict__ y, const float* __restrict__ filt,
    const int* __restrict__ rowptr, const int* __restrict__ cnt,
    const float* __restrict__ bnp, const float* __restrict__ g1, const float* __restrict__ b1,
    float* __restrict__ agg, float* __restrict__ stats)
{
    __shared__ float sbuf[4][64];
    int t = threadIdx.x;
    int lane = t & 63, wv = t >> 6;
    int node = blockIdx.x * 4 + wv;
    int beg = rowptr[node], end = rowptr[node + 1];
    int es = lane >> 4, fq = lane & 15;
    float4 mu4 = *(const float4*)(bnp + fq * 4);
    float4 rs4 = *(const float4*)(bnp + 64 + fq * 4);
    float4 ga4 = *(const float4*)(g1 + fq * 4);
    float4 be4 = *(const float4*)(b1 + fq * 4);

    float fm = -INFINITY;
    for (int i = beg + lane; i < end; i += 64) fm = fmaxf(fm, filt[i]);
    #pragma unroll
    for (int o = 32; o > 0; o >>= 1) fm = fmaxf(fm, __shfl_xor(fm, o, 64));

    float a0 = 0.f, a1 = 0.f, a2 = 0.f, a3 = 0.f, ss = 0.f;
    #pragma unroll 2
    for (int base = beg; base < end; base += 4) {
        int ee = base + es;
        int eec = min(ee, end - 1);
        float wgt = (ee < end) ? expf(filt[eec] - fm) : 0.f;
        ushort4 yv = *(const ushort4*)(y + (size_t)eec * F + fq * 4);
        float c0 = fmaxf((bf2f(yv.x) - mu4.x) * rs4.x * ga4.x + be4.x, 0.f);
        float c1 = fmaxf((bf2f(yv.y) - mu4.y) * rs4.y * ga4.y + be4.y, 0.f);
        float c2 = fmaxf((bf2f(yv.z) - mu4.z) * rs4.z * ga4.z + be4.z, 0.f);
        float c3 = fmaxf((bf2f(yv.w) - mu4.w) * rs4.w * ga4.w + be4.w, 0.f);
        a0 += wgt * c0; a1 += wgt * c1; a2 += wgt * c2; a3 += wgt * c3;
        ss += wgt;
    }
    #pragma unroll
    for (int o = 16; o <= 32; o <<= 1) {
        a0 += __shfl_xor(a0, o, 64);
        a1 += __shfl_xor(a1, o, 64);
        a2 += __shfl_xor(a2, o, 64);
        a3 += __shfl_xor(a3, o, 64);
        ss += __shfl_xor(ss, o, 64);
    }
    float dn = fmaxf((float)cnt[node], 1.f);
    float inv = 1.f / ((ss + 1e-16f) * dn);
    float o0 = a0 * inv, o1 = a1 * inv, o2 = a2 * inv, o3 = a3 * inv;
    if (lane < 16) {
        float4 o4;
        o4.x = o0; o4.y = o1; o4.z = o2; o4.w = o3;
        *(float4*)(agg + (size_t)node * F + fq * 4) = o4;
        sbuf[wv][fq * 4 + 0] = o0;
        sbuf[wv][fq * 4 + 1] = o1;
        sbuf[wv][fq * 4 + 2] = o2;
        sbuf[wv][fq * 4 + 3] = o3;
    }
    __syncthreads();
    int slot = (blockIdx.x & (SLOTS - 1)) * 128;
    if (t < 64) {
        float s2 = sbuf[0][t] + sbuf[1][t] + sbuf[2][t] + sbuf[3][t];
        atomicAdd(&stats[slot + t], s2);
    }
    __syncthreads();
    if (lane < 16) {
        sbuf[wv][fq * 4 + 0] = o0 * o0;
        sbuf[wv][fq * 4 + 1] = o1 * o1;
        sbuf[wv][fq * 4 + 2] = o2 * o2;
        sbuf[wv][fq * 4 + 3] = o3 * o3;
    }
    __syncthreads();
    if (t < 64) {
        float q2 = sbuf[0][t] + sbuf[1][t] + sbuf[2][t] + sbuf[3][t];
        atomicAdd(&stats[slot + 64 + t], q2);
    }
}

__global__ void k_node_upd(const float* __restrict__ agg, const float* __restrict__ bnp,
                           const float* __restrict__ g2, const float* __restrict__ b2,
                           const float* __restrict__ xin, float* __restrict__ xout,
                           unsigned short* __restrict__ xbout) {
    int idx = blockIdx.x * 256 + threadIdx.x;
    if (idx < N_ATOMS * F) {
        int f = idx & 63;
        float v = (agg[idx] - bnp[f]) * bnp[64 + f] * g2[f] + b2[f] + xin[idx];
        v = fmaxf(v, 0.f);
        xout[idx] = v;
        xbout[idx] = f2bf(v);
    }
}

// ---------------- head ----------------

__global__ __launch_bounds__(256) void k_head(
    const float* __restrict__ x, const int* __restrict__ target,
    const float* __restrict__ Wfc, const float* __restrict__ bfc,
    const float* __restrict__ Ws, const float* __restrict__ bs,
    float* __restrict__ out)
{
    __shared__ float hbuf[4][64];
    int t = threadIdx.x;
    int lane = t & 63, w = t >> 6;
    int tt = blockIdx.x * 4 + w;
    int a = target[min(tt, T_TGT - 1)];
    float h = fmaxf(x[(size_t)a * F + lane], 0.f);
    hbuf[w][lane] = h;
    __syncthreads();
    float acc = bfc[lane];
    #pragma unroll 8
    for (int k = 0; k < F; ++k) acc += hbuf[w][k] * Wfc[lane * F + k];
    float h2 = fmaxf(acc, 0.f);
    float p0 = h2 * Ws[lane];
    float p1 = h2 * Ws[F + lane];
    #pragma unroll
    for (int o = 32; o > 0; o >>= 1) {
        p0 += __shfl_xor(p0, o, 64);
        p1 += __shfl_xor(p1, o, 64);
    }
    if (lane == 0 && tt < T_TGT) {
        float l0 = p0 + bs[0], l1 = p1 + bs[1];
        float mx = fmaxf(l0, l1);
        float e0v = expf(l0 - mx), e1v = expf(l1 - mx);
        float inv = 1.f / (e0v + e1v);
        out[tt * 2 + 0] = e0v * inv;
        out[tt * 2 + 1] = e1v * inv;
    }
}

// ---------------- launch ----------------

extern "C" void kernel_launch(void* const* d_in, const int* in_sizes, int n_in,
                              void* d_out, int out_size, void* d_ws, size_t ws_size,
                              hipStream_t stream)
{
    const int*   x_types = (const int*)d_in[0];
    const int*   eidx    = (const int*)d_in[1];
    const float* ea      = (const float*)d_in[2];
    const int*   target  = (const int*)d_in[3];
    const float* emb     = (const float*)d_in[4];
    const float* Wc      = (const float*)d_in[5];
    const float* Wf      = (const float*)d_in[7];
    const float* g1      = (const float*)d_in[9];
    const float* b1      = (const float*)d_in[10];
    const float* g2      = (const float*)d_in[11];
    const float* b2      = (const float*)d_in[12];
    const float* Wfc     = (const float*)d_in[13];
    const float* bfc     = (const float*)d_in[14];
    const float* Ws      = (const float*)d_in[15];
    const float* bs      = (const float*)d_in[16];
    float* out = (float*)d_out;
    const int* idx_i = eidx;
    const int* idx_j = eidx + N_EDGES;

    char* p = (char*)d_ws;
    auto alloc = [&](size_t bytes) {
        char* r = p;
        p += (bytes + 255) & ~(size_t)255;
        return r;
    };
    float* xa            = (float*)alloc((size_t)N_ATOMS * F * 4);
    float* xb_f          = (float*)alloc((size_t)N_ATOMS * F * 4);
    unsigned short* x16a = (unsigned short*)alloc((size_t)N_ATOMS * F * 2);
    unsigned short* x16b = (unsigned short*)alloc((size_t)N_ATOMS * F * 2);
    unsigned short* eab  = (unsigned short*)alloc((size_t)N_EDGES * F * 2);
    unsigned short* ybuf = (unsigned short*)alloc((size_t)N_EDGES * F * 2);
    float* filt          = (float*)alloc((size_t)N_EDGES * 4);
    float* ubuf          = (float*)alloc((size_t)N_ATOMS * F * 4);
    unsigned short* vbuf = (unsigned short*)alloc((size_t)N_ATOMS * F * 2);
    float* pi            = (float*)alloc((size_t)N_ATOMS * 4);
    float* pj            = (float*)alloc((size_t)N_ATOMS * 4);
    float* agg           = (float*)alloc((size_t)N_ATOMS * F * 4);
    int* cnt             = (int*)alloc((size_t)N_ATOMS * 4);
    int* rowptr          = (int*)alloc((size_t)(N_ATOMS + 1) * 4);
    int* wofs            = (int*)alloc((size_t)N_ATOMS * 4);
    int* i_s             = (int*)alloc((size_t)N_EDGES * 4);
    int* j_s             = (int*)alloc((size_t)N_EDGES * 4);
    int* einv            = (int*)alloc((size_t)N_EDGES * 4);
    int* bsum            = (int*)alloc(256 * 4);
    float* stats         = (float*)alloc((size_t)SLOTS * 128 * 4);
    float* bnp1          = (float*)alloc(128 * 4);
    float* bnp2          = (float*)alloc(128 * 4);
    (void)ws_size; (void)in_sizes; (void)n_in; (void)out_size;

    hipMemsetAsync(cnt, 0, (size_t)N_ATOMS * 4, stream);
    hipMemsetAsync(wofs, 0, (size_t)N_ATOMS * 4, stream);
    hipMemsetAsync(stats, 0, (size_t)SLOTS * 128 * 4, stream);   // k_finbn re-zeroes thereafter
    k_embed<<<(N_ATOMS * F + 255) / 256, 256, 0, stream>>>(x_types, emb, xa, x16a);
    k_degree<<<(N_EDGES + 255) / 256, 256, 0, stream>>>(idx_i, cnt);
    k_scanA<<<NB_SCAN, 256, 0, stream>>>(cnt, bsum);
    k_scanB<<<1, 256, 0, stream>>>(bsum, rowptr);
    k_scanC<<<NB_SCAN, 256, 0, stream>>>(cnt, bsum, rowptr);
    k_scatter<<<(N_EDGES + 255) / 256, 256, 0, stream>>>(idx_i, idx_j, rowptr, wofs,
                                                         i_s, j_s, einv);
    k_prep2<<<(N_EDGES * 8) / 256, 256, 0, stream>>>(ea, einv, eab);

    float* xcur = xa;
    float* xnxt = xb_f;
    unsigned short* x16cur = x16a;
    unsigned short* x16nxt = x16b;
    for (int l = 0; l < NCONV; ++l) {
        k_node_mm<<<NBLK_N, 256, 0, stream>>>(x16cur,
            Wc + (size_t)l * F * Z, Wf + (size_t)l * Z, ubuf, vbuf, pi, pj);
        k_edge2<<<NBLK_E, 256, 0, stream>>>(
            eab, ubuf, vbuf, i_s, j_s,
            Wc + (size_t)l * F * Z, Wf + (size_t)l * Z,
            pi, pj,
            ybuf, filt, stats);
        k_finbn<<<1, 64, 0, stream>>>(stats, bnp1, (float)N_EDGES);
        k_node_agg<<<N_ATOMS / 4, 256, 0, stream>>>(ybuf, filt, rowptr, cnt, bnp1,
                                                    g1 + (size_t)l * F, b1 + (size_t)l * F,
                                                    agg, stats);
        k_finbn<<<1, 64, 0, stream>>>(stats, bnp2, (float)N_ATOMS);
        k_node_upd<<<(N_ATOMS * F + 255) / 256, 256, 0, stream>>>(
            agg, bnp2, g2 + (size_t)l * F, b2 + (size_t)l * F, xcur, xnxt, x16nxt);
        float* tf = xcur; xcur = xnxt; xnxt = tf;
        unsigned short* ts = x16cur; x16cur = x16nxt; x16nxt = ts;
    }
    k_head<<<T_TGT / 4, 256, 0, stream>>>(xcur, target, Wfc, bfc, Ws, bs, out);
}

// Round 12
// 695.286 us; speedup vs baseline: 1.7852x; 1.0053x over previous
//
#include <hip/hip_runtime.h>
#include <math.h>

#define N_ATOMS 50000
#define N_EDGES 800000
#define F 64
#define Z 192
#define NCONV 3
#define T_TGT 4096
#define EPS 1e-5f
#define SLOTS 128
#define NB_SCAN 196          // ceil(50000/256)
#define NBLK_E 2500          // edge kernel blocks: 2500*64*5 = 800000
#define STEPS_E 5
#define NGRP_N 3125          // 50000/16 node groups
#define NBLK_N 782           // ceil(3125/4)

typedef __attribute__((ext_vector_type(4))) float f32x4;
typedef __attribute__((ext_vector_type(8))) short s16x8;
typedef __attribute__((ext_vector_type(8))) __bf16 bf16x8;

static_assert(NBLK_E * 64 * STEPS_E == N_EDGES, "edge tiling exact");

static __device__ __forceinline__ float bf2f(unsigned short u) {
    return __uint_as_float(((unsigned int)u) << 16);
}
static __device__ __forceinline__ unsigned short f2bf(float f) {
    unsigned int u = __float_as_uint(f);
    unsigned int r = u + 0x7FFFu + ((u >> 16) & 1u);
    return (unsigned short)(r >> 16);
}
static __device__ __forceinline__ bf16x8 pack8(float4 a, float4 b) {
    s16x8 r;
    r[0] = (short)f2bf(a.x); r[1] = (short)f2bf(a.y);
    r[2] = (short)f2bf(a.z); r[3] = (short)f2bf(a.w);
    r[4] = (short)f2bf(b.x); r[5] = (short)f2bf(b.y);
    r[6] = (short)f2bf(b.z); r[7] = (short)f2bf(b.w);
    return __builtin_bit_cast(bf16x8, r);
}
static __device__ __forceinline__ uint2 pack4(float a, float b, float c, float d) {
    uint2 r;
    r.x = (unsigned int)f2bf(a) | ((unsigned int)f2bf(b) << 16);
    r.y = (unsigned int)f2bf(c) | ((unsigned int)f2bf(d) << 16);
    return r;
}

// ---------------- preprocessing ----------------

__global__ void k_embed(const int* __restrict__ types, const float* __restrict__ emb,
                        float* __restrict__ x, unsigned short* __restrict__ xb) {
    int idx = blockIdx.x * 256 + threadIdx.x;
    if (idx < N_ATOMS * F) {
        int n = idx >> 6, f = idx & 63;
        float v = emb[types[n] * F + f];
        x[idx] = v;
        xb[idx] = f2bf(v);
    }
}

__global__ void k_degree(const int* __restrict__ idx_i, int* __restrict__ cnt) {
    int e = blockIdx.x * 256 + threadIdx.x;
    if (e < N_EDGES) atomicAdd(&cnt[idx_i[e]], 1);
}

__global__ void k_scanA(const int* __restrict__ cnt, int* __restrict__ bsum) {
    __shared__ int s[256];
    int base = blockIdx.x * 256, t = threadIdx.x;
    s[t] = (base + t < N_ATOMS) ? cnt[base + t] : 0;
    __syncthreads();
    for (int o = 128; o > 0; o >>= 1) {
        if (t < o) s[t] += s[t + o];
        __syncthreads();
    }
    if (t == 0) bsum[blockIdx.x] = s[0];
}

__global__ void k_scanB(int* __restrict__ bsum, int* __restrict__ rowptr) {
    __shared__ int s[256];
    int t = threadIdx.x;
    int v = (t < NB_SCAN) ? bsum[t] : 0;
    s[t] = v;
    __syncthreads();
    for (int o = 1; o < 256; o <<= 1) {
        int add = (t >= o) ? s[t - o] : 0;
        __syncthreads();
        s[t] += add;
        __syncthreads();
    }
    if (t < NB_SCAN) bsum[t] = s[t] - v;  // exclusive
    if (t == 0) rowptr[N_ATOMS] = N_EDGES;
}

__global__ void k_scanC(const int* __restrict__ cnt, const int* __restrict__ bsum,
                        int* __restrict__ rowptr) {
    __shared__ int s[256];
    int base = blockIdx.x * 256, t = threadIdx.x;
    int v = (base + t < N_ATOMS) ? cnt[base + t] : 0;
    s[t] = v;
    __syncthreads();
    for (int o = 1; o < 256; o <<= 1) {
        int add = (t >= o) ? s[t - o] : 0;
        __syncthreads();
        s[t] += add;
        __syncthreads();
    }
    if (base + t < N_ATOMS) rowptr[base + t] = bsum[blockIdx.x] + s[t] - v;
}

__global__ void k_scatter(const int* __restrict__ idx_i, const int* __restrict__ idx_j,
                          const int* __restrict__ rowptr, int* __restrict__ wofs,
                          int* __restrict__ i_s, int* __restrict__ j_s,
                          int* __restrict__ einv) {
    int e = blockIdx.x * 256 + threadIdx.x;
    if (e < N_EDGES) {
        int i = idx_i[e];
        int pos = rowptr[i] + atomicAdd(&wofs[i], 1);
        i_s[pos] = i;
        j_s[pos] = idx_j[e];
        einv[e] = pos;              // inverse perm: original edge -> CSR slot
    }
}

// edge_attr -> bf16 into CSR slot. 8 lanes per row: reads are wave-contiguous
// (2 KB/wave), each dest 128-B line is covered by ONE store instruction.
__global__ void k_prep2(const float* __restrict__ ea, const int* __restrict__ einv,
                        unsigned short* __restrict__ eab) {
    int idx = blockIdx.x * 256 + threadIdx.x;
    int row = idx >> 3;
    if (row >= N_EDGES) return;
    int seg = (idx & 7) * 8;
    const float* src = ea + (size_t)row * F + seg;
    float4 a = *(const float4*)src;
    float4 b = *(const float4*)(src + 4);
    int pos = einv[row];
    *(bf16x8*)(eab + (size_t)pos * F + seg) = pack8(a, b);
}

// ---------------- per-layer: node projections (MFMA) ----------------
// u[n] = x[n] @ Wc[:,0:64]^T   (fp32)
// v[n] = x[n] @ Wc[:,64:128]^T (bf16)
// pi[n] = x[n].Wf[0:64], pj[n] = x[n].Wf[64:128]
__global__ __launch_bounds__(256) void k_node_mm(
    const unsigned short* __restrict__ xb,
    const float* __restrict__ Wc, const float* __restrict__ Wf,
    float* __restrict__ u, unsigned short* __restrict__ v,
    float* __restrict__ pi, float* __restrict__ pj)
{
    __shared__ unsigned short WL[18 * 64 * 8];   // 9 KB: frag f = kt*9+m
    int t = threadIdx.x;
    int lane = t & 63, w = t >> 6;
    int c = lane & 15, g = lane >> 4;
    int goff = g * 8;

    #pragma unroll
    for (int rep = 0; rep < 5; ++rep) {
        int f = rep * 4 + w;
        if (f < 18) {
            int kt = f / 9, m = f % 9;           // wave-uniform
            bf16x8 val;
            if (m < 8) {
                int colbase = (m < 4) ? 0 : 64;
                const float* wp = Wc + (size_t)((m & 3) * 16 + c) * Z + colbase + kt * 32 + goff;
                val = pack8(*(const float4*)wp, *(const float4*)(wp + 4));
            } else {
                s16x8 zz = {0, 0, 0, 0, 0, 0, 0, 0};
                val = __builtin_bit_cast(bf16x8, zz);
                if (c == 0) {
                    const float* wp = Wf + kt * 32 + goff;
                    val = pack8(*(const float4*)wp, *(const float4*)(wp + 4));
                } else if (c == 1) {
                    const float* wp = Wf + 64 + kt * 32 + goff;
                    val = pack8(*(const float4*)wp, *(const float4*)(wp + 4));
                }
            }
            *(bf16x8*)(WL + ((size_t)f * 64 + lane) * 8) = val;
        }
    }
    __syncthreads();

    int grp = blockIdx.x * 4 + w;
    if (grp >= NGRP_N) return;
    int node = grp * 16 + c;
    const unsigned short* xr = xb + (size_t)node * F;
    bf16x8 X0 = *(const bf16x8*)(xr + goff);
    bf16x8 X1 = *(const bf16x8*)(xr + 32 + goff);

    #define LFR(f) (*(const bf16x8*)(WL + ((size_t)(f) * 64 + lane) * 8))
    f32x4 au[4], av[4], ap = (f32x4){0.f, 0.f, 0.f, 0.f};
    #pragma unroll
    for (int m = 0; m < 4; ++m) {
        au[m] = (f32x4){0.f, 0.f, 0.f, 0.f};
        av[m] = (f32x4){0.f, 0.f, 0.f, 0.f};
        au[m] = __builtin_amdgcn_mfma_f32_16x16x32_bf16(LFR(m), X0, au[m], 0, 0, 0);
        au[m] = __builtin_amdgcn_mfma_f32_16x16x32_bf16(LFR(9 + m), X1, au[m], 0, 0, 0);
        av[m] = __builtin_amdgcn_mfma_f32_16x16x32_bf16(LFR(4 + m), X0, av[m], 0, 0, 0);
        av[m] = __builtin_amdgcn_mfma_f32_16x16x32_bf16(LFR(13 + m), X1, av[m], 0, 0, 0);
    }
    ap = __builtin_amdgcn_mfma_f32_16x16x32_bf16(LFR(8), X0, ap, 0, 0, 0);
    ap = __builtin_amdgcn_mfma_f32_16x16x32_bf16(LFR(17), X1, ap, 0, 0, 0);
    #undef LFR

    float* urow = u + (size_t)node * F + g * 4;
    unsigned short* vrow = v + (size_t)node * F + g * 4;
    #pragma unroll
    for (int m = 0; m < 4; ++m) {
        *(f32x4*)(urow + m * 16) = au[m];
        *(uint2*)(vrow + m * 16) = pack4(av[m][0], av[m][1], av[m][2], av[m][3]);
    }
    if (g == 0) {
        pi[node] = ap[0];
        pj[node] = ap[1];
    }
}

// ---------------- fused: BN2+residual+ReLU update THEN projections ----------------
// x' = relu(BN2(agg)*g2+b2 + xin); writes x' (fp32) and computes u/v/pi/pj from
// bf16(x') in-register -- no bf16 mirror buffer, no separate upd kernel.
__global__ __launch_bounds__(256) void k_upd_mm(
    const float* __restrict__ agg, const float* __restrict__ bnp,
    const float* __restrict__ g2, const float* __restrict__ b2,
    const float* __restrict__ xin, float* __restrict__ xout,
    const float* __restrict__ Wc, const float* __restrict__ Wf,
    float* __restrict__ u, unsigned short* __restrict__ v,
    float* __restrict__ pi, float* __restrict__ pj)
{
    __shared__ unsigned short WL[18 * 64 * 8];   // 9 KB
    __shared__ float bnl[4][64];                 // mu, rstd, gamma, beta
    int t = threadIdx.x;
    int lane = t & 63, w = t >> 6;
    int c = lane & 15, g = lane >> 4;
    int goff = g * 8;

    #pragma unroll
    for (int rep = 0; rep < 5; ++rep) {
        int f = rep * 4 + w;
        if (f < 18) {
            int kt = f / 9, m = f % 9;
            bf16x8 val;
            if (m < 8) {
                int colbase = (m < 4) ? 0 : 64;
                const float* wp = Wc + (size_t)((m & 3) * 16 + c) * Z + colbase + kt * 32 + goff;
                val = pack8(*(const float4*)wp, *(const float4*)(wp + 4));
            } else {
                s16x8 zz = {0, 0, 0, 0, 0, 0, 0, 0};
                val = __builtin_bit_cast(bf16x8, zz);
                if (c == 0) {
                    const float* wp = Wf + kt * 32 + goff;
                    val = pack8(*(const float4*)wp, *(const float4*)(wp + 4));
                } else if (c == 1) {
                    const float* wp = Wf + 64 + kt * 32 + goff;
                    val = pack8(*(const float4*)wp, *(const float4*)(wp + 4));
                }
            }
            *(bf16x8*)(WL + ((size_t)f * 64 + lane) * 8) = val;
        }
    }
    if (t < 64) {
        bnl[0][t] = bnp[t];
        bnl[1][t] = bnp[64 + t];
        bnl[2][t] = g2[t];
        bnl[3][t] = b2[t];
    }
    __syncthreads();

    int grp = blockIdx.x * 4 + w;
    if (grp >= NGRP_N) return;
    int node = grp * 16 + c;
    const float* ar = agg + (size_t)node * F;
    const float* xr = xin + (size_t)node * F;

    float xv0[8], xv1[8];
    {
        float4 a0 = *(const float4*)(ar + goff);
        float4 a0b = *(const float4*)(ar + goff + 4);
        float4 a1 = *(const float4*)(ar + 32 + goff);
        float4 a1b = *(const float4*)(ar + 32 + goff + 4);
        float4 x0 = *(const float4*)(xr + goff);
        float4 x0b = *(const float4*)(xr + goff + 4);
        float4 x1 = *(const float4*)(xr + 32 + goff);
        float4 x1b = *(const float4*)(xr + 32 + goff + 4);
        float av0[8] = {a0.x, a0.y, a0.z, a0.w, a0b.x, a0b.y, a0b.z, a0b.w};
        float av1[8] = {a1.x, a1.y, a1.z, a1.w, a1b.x, a1b.y, a1b.z, a1b.w};
        float xw0[8] = {x0.x, x0.y, x0.z, x0.w, x0b.x, x0b.y, x0b.z, x0b.w};
        float xw1[8] = {x1.x, x1.y, x1.z, x1.w, x1b.x, x1b.y, x1b.z, x1b.w};
        #pragma unroll
        for (int q = 0; q < 8; ++q) {
            int f0 = goff + q, f1 = 32 + goff + q;
            xv0[q] = fmaxf((av0[q] - bnl[0][f0]) * bnl[1][f0] * bnl[2][f0] + bnl[3][f0] + xw0[q], 0.f);
            xv1[q] = fmaxf((av1[q] - bnl[0][f1]) * bnl[1][f1] * bnl[2][f1] + bnl[3][f1] + xw1[q], 0.f);
        }
        float4 o;
        o.x = xv0[0]; o.y = xv0[1]; o.z = xv0[2]; o.w = xv0[3];
        *(float4*)(xout + (size_t)node * F + goff) = o;
        o.x = xv0[4]; o.y = xv0[5]; o.z = xv0[6]; o.w = xv0[7];
        *(float4*)(xout + (size_t)node * F + goff + 4) = o;
        o.x = xv1[0]; o.y = xv1[1]; o.z = xv1[2]; o.w = xv1[3];
        *(float4*)(xout + (size_t)node * F + 32 + goff) = o;
        o.x = xv1[4]; o.y = xv1[5]; o.z = xv1[6]; o.w = xv1[7];
        *(float4*)(xout + (size_t)node * F + 32 + goff + 4) = o;
    }
    s16x8 px0, px1;
    #pragma unroll
    for (int q = 0; q < 8; ++q) {
        px0[q] = (short)f2bf(xv0[q]);
        px1[q] = (short)f2bf(xv1[q]);
    }
    bf16x8 X0 = __builtin_bit_cast(bf16x8, px0);
    bf16x8 X1 = __builtin_bit_cast(bf16x8, px1);

    #define LFR(f) (*(const bf16x8*)(WL + ((size_t)(f) * 64 + lane) * 8))
    f32x4 au[4], av[4], ap = (f32x4){0.f, 0.f, 0.f, 0.f};
    #pragma unroll
    for (int m = 0; m < 4; ++m) {
        au[m] = (f32x4){0.f, 0.f, 0.f, 0.f};
        av[m] = (f32x4){0.f, 0.f, 0.f, 0.f};
        au[m] = __builtin_amdgcn_mfma_f32_16x16x32_bf16(LFR(m), X0, au[m], 0, 0, 0);
        au[m] = __builtin_amdgcn_mfma_f32_16x16x32_bf16(LFR(9 + m), X1, au[m], 0, 0, 0);
        av[m] = __builtin_amdgcn_mfma_f32_16x16x32_bf16(LFR(4 + m), X0, av[m], 0, 0, 0);
        av[m] = __builtin_amdgcn_mfma_f32_16x16x32_bf16(LFR(13 + m), X1, av[m], 0, 0, 0);
    }
    ap = __builtin_amdgcn_mfma_f32_16x16x32_bf16(LFR(8), X0, ap, 0, 0, 0);
    ap = __builtin_amdgcn_mfma_f32_16x16x32_bf16(LFR(17), X1, ap, 0, 0, 0);
    #undef LFR

    float* urow = u + (size_t)node * F + g * 4;
    unsigned short* vrow = v + (size_t)node * F + g * 4;
    #pragma unroll
    for (int m = 0; m < 4; ++m) {
        *(f32x4*)(urow + m * 16) = au[m];
        *(uint2*)(vrow + m * 16) = pack4(av[m][0], av[m][1], av[m][2], av[m][3]);
    }
    if (g == 0) {
        pi[node] = ap[0];
        pj[node] = ap[1];
    }
}

// ---------------- per-layer: edge kernel (streaming K=64 MFMA + row adds) ----------------
// D[row=feat, col=edge]: lane (c,g) owns edge base+c, feats nt*16+g*4+q.
// nt==4 is the filt column: A-rows = (row0: Wf[128:192], rest 0).
// Round-7 proven body: plain loop (compiler unrolls + schedules), (256,3).
__global__ __launch_bounds__(256, 3) void k_edge2(
    const unsigned short* __restrict__ eab,
    const float* __restrict__ u, const unsigned short* __restrict__ v,
    const int* __restrict__ i_s, const int* __restrict__ j_s,
    const float* __restrict__ Wc, const float* __restrict__ Wf,
    const float* __restrict__ pi, const float* __restrict__ pj,
    unsigned short* __restrict__ y, float* __restrict__ filt,
    float* __restrict__ stats)
{
    __shared__ unsigned short WL[10 * 64 * 8];   // 10 frags: f = kt*5+nt
    int t = threadIdx.x;
    int lane = t & 63, w = t >> 6;
    int c = lane & 15, g = lane >> 4;
    int goff = g * 8;

    #pragma unroll
    for (int rep = 0; rep < 3; ++rep) {
        int f = rep * 4 + w;                     // 0..11, wave-uniform
        if (f < 10) {
            int kt = f / 5, nt = f % 5;
            bf16x8 val;
            if (nt < 4) {
                const float* wp = Wc + (size_t)(nt * 16 + c) * Z + 128 + kt * 32 + goff;
                val = pack8(*(const float4*)wp, *(const float4*)(wp + 4));
            } else {
                s16x8 zz = {0, 0, 0, 0, 0, 0, 0, 0};
                val = __builtin_bit_cast(bf16x8, zz);
                if (c == 0) {
                    const float* wp = Wf + 128 + kt * 32 + goff;
                    val = pack8(*(const float4*)wp, *(const float4*)(wp + 4));
                }
            }
            *(bf16x8*)(WL + ((size_t)f * 64 + lane) * 8) = val;
        }
    }
    __syncthreads();

    bf16x8 A[2][5];
    #pragma unroll
    for (int kt = 0; kt < 2; ++kt)
        #pragma unroll
        for (int nt = 0; nt < 5; ++nt)
            A[kt][nt] = *(const bf16x8*)(WL + ((size_t)(kt * 5 + nt) * 64 + lane) * 8);

    float ssum[4][4] = {{0.f}}, ssq[4][4] = {{0.f}};

    int e = blockIdx.x * (STEPS_E * 64) + w * 16 + c;
    int ie = i_s[e], je = j_s[e];
    bf16x8 E0 = *(const bf16x8*)(eab + (size_t)e * F + goff);
    bf16x8 E1 = *(const bf16x8*)(eab + (size_t)e * F + 32 + goff);

    for (int s = 0; s < STEPS_E; ++s) {
        // u/v row loads for current edge (addresses ready since last iter)
        const float* ur = u + (size_t)ie * F + g * 4;
        const unsigned short* vr = v + (size_t)je * F + g * 4;
        float4 uu[4];
        uint2 vv[4];
        #pragma unroll
        for (int nt = 0; nt < 4; ++nt) {
            uu[nt] = *(const float4*)(ur + nt * 16);
            vv[nt] = *(const uint2*)(vr + nt * 16);
        }
        float fi = 0.f, fj = 0.f;
        if (g == 0) { fi = pi[ie]; fj = pj[je]; }

        // prefetch next step
        int e2 = e, ie2 = ie, je2 = je;
        bf16x8 E0n = E0, E1n = E1;
        if (s + 1 < STEPS_E) {
            e2 = e + 64;
            ie2 = i_s[e2];
            je2 = j_s[e2];
            E0n = *(const bf16x8*)(eab + (size_t)e2 * F + goff);
            E1n = *(const bf16x8*)(eab + (size_t)e2 * F + 32 + goff);
        }

        f32x4 acc[5];
        #pragma unroll
        for (int nt = 0; nt < 5; ++nt) {
            acc[nt] = (f32x4){0.f, 0.f, 0.f, 0.f};
            acc[nt] = __builtin_amdgcn_mfma_f32_16x16x32_bf16(A[0][nt], E0, acc[nt], 0, 0, 0);
            acc[nt] = __builtin_amdgcn_mfma_f32_16x16x32_bf16(A[1][nt], E1, acc[nt], 0, 0, 0);
        }

        unsigned short* yr = y + (size_t)e * F + g * 4;
        #pragma unroll
        for (int nt = 0; nt < 4; ++nt) {
            float y0 = acc[nt][0] + uu[nt].x + bf2f((unsigned short)(vv[nt].x & 0xffff));
            float y1 = acc[nt][1] + uu[nt].y + bf2f((unsigned short)(vv[nt].x >> 16));
            float y2 = acc[nt][2] + uu[nt].z + bf2f((unsigned short)(vv[nt].y & 0xffff));
            float y3 = acc[nt][3] + uu[nt].w + bf2f((unsigned short)(vv[nt].y >> 16));
            ssum[nt][0] += y0; ssq[nt][0] += y0 * y0;
            ssum[nt][1] += y1; ssq[nt][1] += y1 * y1;
            ssum[nt][2] += y2; ssq[nt][2] += y2 * y2;
            ssum[nt][3] += y3; ssq[nt][3] += y3 * y3;
            *(uint2*)(yr + nt * 16) = pack4(y0, y1, y2, y3);
        }
        if (g == 0) filt[e] = acc[4][0] + fi + fj;

        e = e2; ie = ie2; je = je2; E0 = E0n; E1 = E1n;
    }

    // stats: reduce over the 16 c-lanes, atomic per feature
    int slot = (blockIdx.x & (SLOTS - 1)) * 128;
    #pragma unroll
    for (int nt = 0; nt < 4; ++nt) {
        #pragma unroll
        for (int q = 0; q < 4; ++q) {
            float S = ssum[nt][q], Q = ssq[nt][q];
            S += __shfl_xor(S, 1, 64); S += __shfl_xor(S, 2, 64);
            S += __shfl_xor(S, 4, 64); S += __shfl_xor(S, 8, 64);
            Q += __shfl_xor(Q, 1, 64); Q += __shfl_xor(Q, 2, 64);
            Q += __shfl_xor(Q, 4, 64); Q += __shfl_xor(Q, 8, 64);
            if (c == 0) {
                int f = nt * 16 + g * 4 + q;
                atomicAdd(&stats[slot + f], S);
                atomicAdd(&stats[slot + 64 + f], Q);
            }
        }
    }
}

// ---------------- per-layer small kernels ----------------

// 256 threads: 4-way slot-split + LDS reduce; zeroes stats for next use.
__global__ void k_finbn(float* __restrict__ stats, float* __restrict__ bnp, float count) {
    __shared__ float red[4][128];
    int t = threadIdx.x;
    int f = t & 63, grp = t >> 6;
    float S = 0.f, Q = 0.f;
    for (int s = grp; s < SLOTS; s += 4) {
        S += stats[s * 128 + f];
        Q += stats[s * 128 + 64 + f];
    }
    red[grp][f] = S;
    red[grp][64 + f] = Q;
    __syncthreads();
    for (int i = t; i < SLOTS * 128; i += 256) stats[i] = 0.f;
    if (t < 64) {
        float Sa = red[0][t] + red[1][t] + red[2][t] + red[3][t];
        float Qa = red[0][64 + t] + red[1][64 + t] + red[2][64 + t] + red[3][64 + t];
        float mu = Sa / count;
        float var = fmaxf(Qa / count - mu * mu, 0.f);
        bnp[t] = mu;
        bnp[64 + t] = 1.f / sqrtf(var + EPS);
    }
}

// wave per node; 4 edges x 16 feature-quads in parallel.
// Fused BN2 stats: block-reduced agg sum/sumsq -> slot-replicated atomics.
__global__ __launch_bounds__(256) void k_node_agg(
    const unsigned short* __restrict__ y, const float* __restrict__ filt,
    const int* __restrict__ rowptr, const int* __restrict__ cnt,
    const float* __restrict__ bnp, const float* __restrict__ g1, const float* __restrict__ b1,
    float* __restrict__ agg, float* __restrict__ stats)
{
    __shared__ float sbuf[4][64];
    int t = threadIdx.x;
    int lane = t & 63, wv = t >> 6;
    int node = blockIdx.x * 4 + wv;
    int beg = rowptr[node], end = rowptr[node + 1];
    int es = lane >> 4, fq = lane & 15;
    float4 mu4 = *(const float4*)(bnp + fq * 4);
    float4 rs4 = *(const float4*)(bnp + 64 + fq * 4);
    float4 ga4 = *(const float4*)(g1 + fq * 4);
    float4 be4 = *(const float4*)(b1 + fq * 4);

    float fm = -INFINITY;
    for (int i = beg + lane; i < end; i += 64) fm = fmaxf(fm, filt[i]);
    #pragma unroll
    for (int o = 32; o > 0; o >>= 1) fm = fmaxf(fm, __shfl_xor(fm, o, 64));

    float a0 = 0.f, a1 = 0.f, a2 = 0.f, a3 = 0.f, ss = 0.f;
    #pragma unroll 2
    for (int base = beg; base < end; base += 4) {
        int ee = base + es;
        int eec = min(ee, end - 1);
        float wgt = (ee < end) ? expf(filt[eec] - fm) : 0.f;
        ushort4 yv = *(const ushort4*)(y + (size_t)eec * F + fq * 4);
        float c0 = fmaxf((bf2f(yv.x) - mu4.x) * rs4.x * ga4.x + be4.x, 0.f);
        float c1 = fmaxf((bf2f(yv.y) - mu4.y) * rs4.y * ga4.y + be4.y, 0.f);
        float c2 = fmaxf((bf2f(yv.z) - mu4.z) * rs4.z * ga4.z + be4.z, 0.f);
        float c3 = fmaxf((bf2f(yv.w) - mu4.w) * rs4.w * ga4.w + be4.w, 0.f);
        a0 += wgt * c0; a1 += wgt * c1; a2 += wgt * c2; a3 += wgt * c3;
        ss += wgt;
    }
    #pragma unroll
    for (int o = 16; o <= 32; o <<= 1) {
        a0 += __shfl_xor(a0, o, 64);
        a1 += __shfl_xor(a1, o, 64);
        a2 += __shfl_xor(a2, o, 64);
        a3 += __shfl_xor(a3, o, 64);
        ss += __shfl_xor(ss, o, 64);
    }
    float dn = fmaxf((float)cnt[node], 1.f);
    float inv = 1.f / ((ss + 1e-16f) * dn);
    float o0 = a0 * inv, o1 = a1 * inv, o2 = a2 * inv, o3 = a3 * inv;
    if (lane < 16) {
        float4 o4;
        o4.x = o0; o4.y = o1; o4.z = o2; o4.w = o3;
        *(float4*)(agg + (size_t)node * F + fq * 4) = o4;
        sbuf[wv][fq * 4 + 0] = o0;
        sbuf[wv][fq * 4 + 1] = o1;
        sbuf[wv][fq * 4 + 2] = o2;
        sbuf[wv][fq * 4 + 3] = o3;
    }
    __syncthreads();
    int slot = (blockIdx.x & (SLOTS - 1)) * 128;
    if (t < 64) {
        float s2 = sbuf[0][t] + sbuf[1][t] + sbuf[2][t] + sbuf[3][t];
        atomicAdd(&stats[slot + t], s2);
    }
    __syncthreads();
    if (lane < 16) {
        sbuf[wv][fq * 4 + 0] = o0 * o0;
        sbuf[wv][fq * 4 + 1] = o1 * o1;
        sbuf[wv][fq * 4 + 2] = o2 * o2;
        sbuf[wv][fq * 4 + 3] = o3 * o3;
    }
    __syncthreads();
    if (t < 64) {
        float q2 = sbuf[0][t] + sbuf[1][t] + sbuf[2][t] + sbuf[3][t];
        atomicAdd(&stats[slot + 64 + t], q2);
    }
}

// final-layer update (fp32 only; nothing consumes a bf16 mirror afterwards)
__global__ void k_node_upd(const float* __restrict__ agg, const float* __restrict__ bnp,
                           const float* __restrict__ g2, const float* __restrict__ b2,
                           const float* __restrict__ xin, float* __restrict__ xout) {
    int idx = blockIdx.x * 256 + threadIdx.x;
    if (idx < N_ATOMS * F) {
        int f = idx & 63;
        float v = (agg[idx] - bnp[f]) * bnp[64 + f] * g2[f] + b2[f] + xin[idx];
        xout[idx] = fmaxf(v, 0.f);
    }
}

// ---------------- head ----------------

__global__ __launch_bounds__(256) void k_head(
    const float* __restrict__ x, const int* __restrict__ target,
    const float* __restrict__ Wfc, const float* __restrict__ bfc,
    const float* __restrict__ Ws, const float* __restrict__ bs,
    float* __restrict__ out)
{
    __shared__ float hbuf[4][64];
    int t = threadIdx.x;
    int lane = t & 63, w = t >> 6;
    int tt = blockIdx.x * 4 + w;
    int a = target[min(tt, T_TGT - 1)];
    float h = fmaxf(x[(size_t)a * F + lane], 0.f);
    hbuf[w][lane] = h;
    __syncthreads();
    float acc = bfc[lane];
    #pragma unroll 8
    for (int k = 0; k < F; ++k) acc += hbuf[w][k] * Wfc[lane * F + k];
    float h2 = fmaxf(acc, 0.f);
    float p0 = h2 * Ws[lane];
    float p1 = h2 * Ws[F + lane];
    #pragma unroll
    for (int o = 32; o > 0; o >>= 1) {
        p0 += __shfl_xor(p0, o, 64);
        p1 += __shfl_xor(p1, o, 64);
    }
    if (lane == 0 && tt < T_TGT) {
        float l0 = p0 + bs[0], l1 = p1 + bs[1];
        float mx = fmaxf(l0, l1);
        float e0v = expf(l0 - mx), e1v = expf(l1 - mx);
        float inv = 1.f / (e0v + e1v);
        out[tt * 2 + 0] = e0v * inv;
        out[tt * 2 + 1] = e1v * inv;
    }
}

// ---------------- launch ----------------

extern "C" void kernel_launch(void* const* d_in, const int* in_sizes, int n_in,
                              void* d_out, int out_size, void* d_ws, size_t ws_size,
                              hipStream_t stream)
{
    const int*   x_types = (const int*)d_in[0];
    const int*   eidx    = (const int*)d_in[1];
    const float* ea      = (const float*)d_in[2];
    const int*   target  = (const int*)d_in[3];
    const float* emb     = (const float*)d_in[4];
    const float* Wc      = (const float*)d_in[5];
    const float* Wf      = (const float*)d_in[7];
    const float* g1      = (const float*)d_in[9];
    const float* b1      = (const float*)d_in[10];
    const float* g2      = (const float*)d_in[11];
    const float* b2      = (const float*)d_in[12];
    const float* Wfc     = (const float*)d_in[13];
    const float* bfc     = (const float*)d_in[14];
    const float* Ws      = (const float*)d_in[15];
    const float* bs      = (const float*)d_in[16];
    float* out = (float*)d_out;
    const int* idx_i = eidx;
    const int* idx_j = eidx + N_EDGES;

    char* p = (char*)d_ws;
    auto alloc = [&](size_t bytes) {
        char* r = p;
        p += (bytes + 255) & ~(size_t)255;
        return r;
    };
    float* xa            = (float*)alloc((size_t)N_ATOMS * F * 4);
    float* xb_f          = (float*)alloc((size_t)N_ATOMS * F * 4);
    unsigned short* x16a = (unsigned short*)alloc((size_t)N_ATOMS * F * 2);
    unsigned short* eab  = (unsigned short*)alloc((size_t)N_EDGES * F * 2);
    unsigned short* ybuf = (unsigned short*)alloc((size_t)N_EDGES * F * 2);
    float* filt          = (float*)alloc((size_t)N_EDGES * 4);
    float* ubuf          = (float*)alloc((size_t)N_ATOMS * F * 4);
    unsigned short* vbuf = (unsigned short*)alloc((size_t)N_ATOMS * F * 2);
    float* pi            = (float*)alloc((size_t)N_ATOMS * 4);
    float* pj            = (float*)alloc((size_t)N_ATOMS * 4);
    float* agg           = (float*)alloc((size_t)N_ATOMS * F * 4);
    int* cnt             = (int*)alloc((size_t)N_ATOMS * 4);
    int* rowptr          = (int*)alloc((size_t)(N_ATOMS + 1) * 4);
    int* wofs            = (int*)alloc((size_t)N_ATOMS * 4);
    int* i_s             = (int*)alloc((size_t)N_EDGES * 4);
    int* j_s             = (int*)alloc((size_t)N_EDGES * 4);
    int* einv            = (int*)alloc((size_t)N_EDGES * 4);
    int* bsum            = (int*)alloc(256 * 4);
    float* stats         = (float*)alloc((size_t)SLOTS * 128 * 4);
    float* bnp1          = (float*)alloc(128 * 4);
    float* bnp2          = (float*)alloc(128 * 4);
    (void)ws_size; (void)in_sizes; (void)n_in; (void)out_size;

    hipMemsetAsync(cnt, 0, (size_t)N_ATOMS * 4, stream);
    hipMemsetAsync(wofs, 0, (size_t)N_ATOMS * 4, stream);
    hipMemsetAsync(stats, 0, (size_t)SLOTS * 128 * 4, stream);   // k_finbn re-zeroes thereafter
    k_embed<<<(N_ATOMS * F + 255) / 256, 256, 0, stream>>>(x_types, emb, xa, x16a);
    k_degree<<<(N_EDGES + 255) / 256, 256, 0, stream>>>(idx_i, cnt);
    k_scanA<<<NB_SCAN, 256, 0, stream>>>(cnt, bsum);
    k_scanB<<<1, 256, 0, stream>>>(bsum, rowptr);
    k_scanC<<<NB_SCAN, 256, 0, stream>>>(cnt, bsum, rowptr);
    k_scatter<<<(N_EDGES + 255) / 256, 256, 0, stream>>>(idx_i, idx_j, rowptr, wofs,
                                                         i_s, j_s, einv);
    k_prep2<<<(N_EDGES * 8) / 256, 256, 0, stream>>>(ea, einv, eab);

    float* xcur = xa;      // fp32 x of current layer input
    float* xnxt = xb_f;
    for (int l = 0; l < NCONV; ++l) {
        if (l == 0) {
            k_node_mm<<<NBLK_N, 256, 0, stream>>>(x16a,
                Wc, Wf, ubuf, vbuf, pi, pj);
        } else {
            // fused: x_{l} = relu(BN2_{l-1}(agg)+x_{l-1}), then projections for layer l
            k_upd_mm<<<NBLK_N, 256, 0, stream>>>(
                agg, bnp2, g2 + (size_t)(l - 1) * F, b2 + (size_t)(l - 1) * F,
                xcur, xnxt,
                Wc + (size_t)l * F * Z, Wf + (size_t)l * Z,
                ubuf, vbuf, pi, pj);
            float* tf = xcur; xcur = xnxt; xnxt = tf;
        }
        k_edge2<<<NBLK_E, 256, 0, stream>>>(
            eab, ubuf, vbuf, i_s, j_s,
            Wc + (size_t)l * F * Z, Wf + (size_t)l * Z,
            pi, pj,
            ybuf, filt, stats);
        k_finbn<<<1, 256, 0, stream>>>(stats, bnp1, (float)N_EDGES);
        k_node_agg<<<N_ATOMS / 4, 256, 0, stream>>>(ybuf, filt, rowptr, cnt, bnp1,
                                                    g1 + (size_t)l * F, b1 + (size_t)l * F,
                                                    agg, stats);
        k_finbn<<<1, 256, 0, stream>>>(stats, bnp2, (float)N_ATOMS);
    }
    // final update (layer NCONV-1's BN2 + residual), fp32 only
    k_node_upd<<<(N_ATOMS * F + 255) / 256, 256, 0, stream>>>(
        agg, bnp2, g2 + (size_t)(NCONV - 1) * F, b2 + (size_t)(NCONV - 1) * F,
        xcur, xnxt);
    k_head<<<T_TGT / 4, 256, 0, stream>>>(xnxt, target, Wfc, bfc, Ws, bs, out);
}